// Round 1
// baseline (768.154 us; speedup 1.0000x reference)
//
#include <hip/hip_runtime.h>

#define N_NODES   50000
#define N_EDGES   10000
#define NNZ_TOT   800000

// ---------------------------------------------------------------------------
// Histogram: count node / hyperedge degrees (also the scatter cursor seeds)
// ---------------------------------------------------------------------------
__global__ __launch_bounds__(256) void hist_kernel(
    const int* __restrict__ node_idx, const int* __restrict__ edge_idx,
    int* __restrict__ cnt_v, int* __restrict__ cnt_e, int nnz)
{
    int k = blockIdx.x * 256 + threadIdx.x;
    if (k < nnz) {
        atomicAdd(&cnt_v[node_idx[k]], 1);
        atomicAdd(&cnt_e[edge_idx[k]], 1);
    }
}

// ---------------------------------------------------------------------------
// Exclusive prefix sum over degree arrays (block 0: edges, block 1: nodes).
// Writes offs[i], resets cnt[i] to offs[i] (scatter cursor), and inv[i]=1/deg.
// Wave-level __shfl_up scans -> only 3 __syncthreads per 1024-chunk.
// ---------------------------------------------------------------------------
__global__ __launch_bounds__(1024) void scan_kernel(
    int* __restrict__ cnt_e, int* __restrict__ offs_e, float* __restrict__ Binv, int ne,
    int* __restrict__ cnt_v, int* __restrict__ offs_v, float* __restrict__ Dinv, int nv)
{
    int* cnt; int* offs; float* inv; int n;
    if (blockIdx.x == 0) { cnt = cnt_e; offs = offs_e; inv = Binv; n = ne; }
    else                 { cnt = cnt_v; offs = offs_v; inv = Dinv; n = nv; }

    __shared__ int wtot[16];
    __shared__ int s_run;
    const int tid  = threadIdx.x;
    const int lane = tid & 63;
    const int w    = tid >> 6;
    if (tid == 0) s_run = 0;
    __syncthreads();

    for (int base = 0; base < n; base += 1024) {
        int i   = base + tid;
        int val = (i < n) ? cnt[i] : 0;

        // wave inclusive scan
        int x = val;
        #pragma unroll
        for (int d = 1; d < 64; d <<= 1) {
            int y = __shfl_up(x, d, 64);
            if (lane >= d) x += y;
        }
        if (lane == 63) wtot[w] = x;
        __syncthreads();
        if (w == 0) {
            int t = (lane < 16) ? wtot[lane] : 0;
            #pragma unroll
            for (int d = 1; d < 16; d <<= 1) {
                int y = __shfl_up(t, d, 64);
                if (lane >= d) t += y;
            }
            if (lane < 16) wtot[lane] = t;   // inclusive wave totals
        }
        __syncthreads();
        int incl = x + ((w > 0) ? wtot[w - 1] : 0);
        int excl = incl - val;
        int run  = s_run;
        if (i < n) {
            int o   = run + excl;
            offs[i] = o;
            cnt[i]  = o;                       // scatter cursor
            inv[i]  = (val > 0) ? (1.0f / (float)val) : 0.0f;
        }
        __syncthreads();
        if (tid == 1023) s_run = run + incl;   // chunk total
        __syncthreads();
    }
    if (threadIdx.x == 0) offs[n] = s_run;
}

// ---------------------------------------------------------------------------
// Scatter incidences into both CSR structures
// ---------------------------------------------------------------------------
__global__ __launch_bounds__(256) void scatter_kernel(
    const int* __restrict__ node_idx, const int* __restrict__ edge_idx,
    int* __restrict__ cur_v, int* __restrict__ cur_e,
    int* __restrict__ csrE_nodes, int* __restrict__ csrV_edges, int nnz)
{
    int k = blockIdx.x * 256 + threadIdx.x;
    if (k < nnz) {
        int v = node_idx[k], e = edge_idx[k];
        int p = atomicAdd(&cur_e[e], 1);
        csrE_nodes[p] = v;
        int q = atomicAdd(&cur_v[v], 1);
        csrV_edges[q] = e;
    }
}

// ---------------------------------------------------------------------------
// fp32 GEMM  Y[N,FOUT] = X[N,FIN] @ W[FIN,FOUT] + bias
// Block: 256 threads, tile BR x FOUT (BR = 4096/FOUT), thread tile 4x4.
// No fp32 MFMA on CDNA4 -> vector FMA with LDS staging.
// ---------------------------------------------------------------------------
template<int FIN, int FOUT>
__global__ __launch_bounds__(256) void gemm_bias(
    const float* __restrict__ X, const float* __restrict__ W,
    const float* __restrict__ Bias, float* __restrict__ Y, int N)
{
    constexpr int BR = 4096 / FOUT;   // rows per block
    constexpr int CG = FOUT / 4;      // threads along cols (each owns 4 cols)
    constexpr int KB = 32;            // k chunk

    __shared__ float Xs[BR][KB + 1];  // +1 pad: kills same-bank aliasing across row groups
    __shared__ float Ws[KB][FOUT];

    const int tid  = threadIdx.x;
    const int cg   = tid % CG;        // col group: cols cg*4 .. cg*4+3
    const int rg   = tid / CG;        // row group: rows rg*4 .. rg*4+3
    const int row0 = blockIdx.x * BR;

    float acc[4][4];
    #pragma unroll
    for (int i = 0; i < 4; ++i)
        #pragma unroll
        for (int j = 0; j < 4; ++j) acc[i][j] = 0.f;

    for (int k0 = 0; k0 < FIN; k0 += KB) {
        #pragma unroll
        for (int t = tid; t < BR * KB; t += 256) {
            int r = t / KB, k = t % KB;
            int gr = row0 + r; if (gr >= N) gr = N - 1;   // clamp: result discarded
            Xs[r][k] = X[gr * FIN + k0 + k];
        }
        #pragma unroll
        for (int t = tid; t < KB * FOUT; t += 256) {
            int k = t / FOUT, c = t % FOUT;
            Ws[k][c] = W[(k0 + k) * FOUT + c];
        }
        __syncthreads();
        #pragma unroll
        for (int k = 0; k < KB; ++k) {
            float4 wv = *(const float4*)&Ws[k][cg * 4];
            float xv0 = Xs[rg * 4 + 0][k];
            float xv1 = Xs[rg * 4 + 1][k];
            float xv2 = Xs[rg * 4 + 2][k];
            float xv3 = Xs[rg * 4 + 3][k];
            acc[0][0] += xv0 * wv.x; acc[0][1] += xv0 * wv.y; acc[0][2] += xv0 * wv.z; acc[0][3] += xv0 * wv.w;
            acc[1][0] += xv1 * wv.x; acc[1][1] += xv1 * wv.y; acc[1][2] += xv1 * wv.z; acc[1][3] += xv1 * wv.w;
            acc[2][0] += xv2 * wv.x; acc[2][1] += xv2 * wv.y; acc[2][2] += xv2 * wv.z; acc[2][3] += xv2 * wv.w;
            acc[3][0] += xv3 * wv.x; acc[3][1] += xv3 * wv.y; acc[3][2] += xv3 * wv.z; acc[3][3] += xv3 * wv.w;
        }
        __syncthreads();
    }

    float4 bv = *(const float4*)&Bias[cg * 4];
    #pragma unroll
    for (int i = 0; i < 4; ++i) {
        int gr = row0 + rg * 4 + i;
        if (gr < N) {
            float4 o;
            o.x = acc[i][0] + bv.x; o.y = acc[i][1] + bv.y;
            o.z = acc[i][2] + bv.z; o.w = acc[i][3] + bv.w;
            *(float4*)&Y[gr * FOUT + cg * 4] = o;
        }
    }
}

// ---------------------------------------------------------------------------
// Segment gather-sum: DST[s,:] = inv[s] * sum_{p in [offs[s],offs[s+1])} SRC[lst[p],:]
// One block per segment; 256/F groups stride over neighbors; LDS cross-group
// reduce. Degree-0 segments write 0 (inv==0), which also zero-fills inactive
// node rows for the next layer's GEMM. RELU applied on the node->out phase.
// ---------------------------------------------------------------------------
template<int F, bool RELU>
__global__ __launch_bounds__(256) void seg_gather_sum(
    const float* __restrict__ SRC, const int* __restrict__ offs,
    const int* __restrict__ lst, const float* __restrict__ inv,
    float* __restrict__ DST)
{
    constexpr int G = 256 / F;
    const int s     = blockIdx.x;
    const int start = offs[s], end = offs[s + 1];
    const int g     = threadIdx.x / F;
    const int c     = threadIdx.x % F;

    float acc = 0.f;
    for (int p = start + g; p < end; p += G) {
        int r = lst[p];
        acc += SRC[r * F + c];
    }

    __shared__ float red[256];
    red[threadIdx.x] = acc;
    __syncthreads();
    if (threadIdx.x < F) {
        float sum = red[threadIdx.x];
        #pragma unroll
        for (int j = 1; j < G; ++j) sum += red[j * F + threadIdx.x];
        float o = sum * inv[s];
        if (RELU) o = fmaxf(o, 0.f);
        DST[s * F + threadIdx.x] = o;
    }
}

// ---------------------------------------------------------------------------
extern "C" void kernel_launch(void* const* d_in, const int* in_sizes, int n_in,
                              void* d_out, int out_size, void* d_ws, size_t ws_size,
                              hipStream_t stream)
{
    const float* x  = (const float*)d_in[0];
    const int* edge = (const int*)d_in[1];     // int32 per harness contract
    const float* w1 = (const float*)d_in[2];
    const float* b1 = (const float*)d_in[3];
    const float* w2 = (const float*)d_in[4];
    const float* b2 = (const float*)d_in[5];
    const float* w3 = (const float*)d_in[6];
    const float* b3 = (const float*)d_in[7];
    float* out = (float*)d_out;

    const int N = N_NODES, E = N_EDGES, NNZ = NNZ_TOT;
    const int* node_idx = edge;          // edge[0,:]
    const int* edge_idx = edge + NNZ;    // edge[1,:]

    uintptr_t base = (uintptr_t)d_ws;
    size_t off = 0;
    auto take = [&](size_t nbytes) -> void* {
        off = (off + 255) & ~(size_t)255;
        void* p = (void*)(base + off);
        off += nbytes;
        return p;
    };
    int*   cur_e  = (int*)  take((size_t)E * 4);
    int*   cur_v  = (int*)  take((size_t)N * 4);
    int*   offs_e = (int*)  take((size_t)(E + 1) * 4);
    int*   offs_v = (int*)  take((size_t)(N + 1) * 4);
    float* Binv   = (float*)take((size_t)E * 4);
    float* Dinv   = (float*)take((size_t)N * 4);
    int*   csrE   = (int*)  take((size_t)NNZ * 4);   // nodes grouped by hyperedge
    int*   csrV   = (int*)  take((size_t)NNZ * 4);   // hyperedges grouped by node
    float* xw     = (float*)take((size_t)N * 128 * 4);
    float* hA     = (float*)take((size_t)N * 128 * 4);
    float* hB     = (float*)take((size_t)N * 64 * 4);
    float* me     = (float*)take((size_t)E * 128 * 4);

    hipMemsetAsync(cur_e, 0, (size_t)E * 4, stream);
    hipMemsetAsync(cur_v, 0, (size_t)N * 4, stream);

    hist_kernel<<<(NNZ + 255) / 256, 256, 0, stream>>>(node_idx, edge_idx, cur_v, cur_e, NNZ);
    scan_kernel<<<2, 1024, 0, stream>>>(cur_e, offs_e, Binv, E, cur_v, offs_v, Dinv, N);
    scatter_kernel<<<(NNZ + 255) / 256, 256, 0, stream>>>(node_idx, edge_idx, cur_v, cur_e, csrE, csrV, NNZ);

    // Layer 1: 128 -> 128
    gemm_bias<128, 128><<<(N + 31) / 32, 256, 0, stream>>>(x, w1, b1, xw, N);
    seg_gather_sum<128, false><<<E, 256, 0, stream>>>(xw, offs_e, csrE, Binv, me);
    seg_gather_sum<128, true ><<<N, 256, 0, stream>>>(me, offs_v, csrV, Dinv, hA);

    // Layer 2: 128 -> 64
    gemm_bias<128, 64><<<(N + 63) / 64, 256, 0, stream>>>(hA, w2, b2, xw, N);
    seg_gather_sum<64, false><<<E, 256, 0, stream>>>(xw, offs_e, csrE, Binv, me);
    seg_gather_sum<64, true ><<<N, 256, 0, stream>>>(me, offs_v, csrV, Dinv, hB);

    // Layer 3: 64 -> 32
    gemm_bias<64, 32><<<(N + 127) / 128, 256, 0, stream>>>(hB, w3, b3, xw, N);
    seg_gather_sum<32, false><<<E, 256, 0, stream>>>(xw, offs_e, csrE, Binv, me);
    seg_gather_sum<32, true ><<<N, 256, 0, stream>>>(me, offs_v, csrV, Dinv, out);
}

// Round 2
// 558.474 us; speedup vs baseline: 1.3755x; 1.3755x over previous
//
#include <hip/hip_runtime.h>

#define N_NODES   50000
#define N_EDGES   10000
#define NNZ_TOT   800000

// ---------------------------------------------------------------------------
// Histogram: count node / hyperedge degrees (also the scatter cursor seeds)
// ---------------------------------------------------------------------------
__global__ __launch_bounds__(256) void hist_kernel(
    const int* __restrict__ node_idx, const int* __restrict__ edge_idx,
    int* __restrict__ cnt_v, int* __restrict__ cnt_e, int nnz)
{
    int k = blockIdx.x * 256 + threadIdx.x;
    if (k < nnz) {
        atomicAdd(&cnt_v[node_idx[k]], 1);
        atomicAdd(&cnt_e[edge_idx[k]], 1);
    }
}

// ---------------------------------------------------------------------------
// Exclusive prefix sum over degree arrays (block 0: edges, block 1: nodes).
// Writes offs[i], resets cnt[i] to offs[i] (scatter cursor), and inv[i]=1/deg.
// ---------------------------------------------------------------------------
__global__ __launch_bounds__(1024) void scan_kernel(
    int* __restrict__ cnt_e, int* __restrict__ offs_e, float* __restrict__ Binv, int ne,
    int* __restrict__ cnt_v, int* __restrict__ offs_v, float* __restrict__ Dinv, int nv)
{
    int* cnt; int* offs; float* inv; int n;
    if (blockIdx.x == 0) { cnt = cnt_e; offs = offs_e; inv = Binv; n = ne; }
    else                 { cnt = cnt_v; offs = offs_v; inv = Dinv; n = nv; }

    __shared__ int wtot[16];
    __shared__ int s_run;
    const int tid  = threadIdx.x;
    const int lane = tid & 63;
    const int w    = tid >> 6;
    if (tid == 0) s_run = 0;
    __syncthreads();

    for (int base = 0; base < n; base += 1024) {
        int i   = base + tid;
        int val = (i < n) ? cnt[i] : 0;

        int x = val;
        #pragma unroll
        for (int d = 1; d < 64; d <<= 1) {
            int y = __shfl_up(x, d, 64);
            if (lane >= d) x += y;
        }
        if (lane == 63) wtot[w] = x;
        __syncthreads();
        if (w == 0) {
            int t = (lane < 16) ? wtot[lane] : 0;
            #pragma unroll
            for (int d = 1; d < 16; d <<= 1) {
                int y = __shfl_up(t, d, 64);
                if (lane >= d) t += y;
            }
            if (lane < 16) wtot[lane] = t;
        }
        __syncthreads();
        int incl = x + ((w > 0) ? wtot[w - 1] : 0);
        int excl = incl - val;
        int run  = s_run;
        if (i < n) {
            int o   = run + excl;
            offs[i] = o;
            cnt[i]  = o;
            inv[i]  = (val > 0) ? (1.0f / (float)val) : 0.0f;
        }
        __syncthreads();
        if (tid == 1023) s_run = run + incl;
        __syncthreads();
    }
    if (threadIdx.x == 0) offs[n] = s_run;
}

// ---------------------------------------------------------------------------
// Scatter incidences into both CSR structures
// ---------------------------------------------------------------------------
__global__ __launch_bounds__(256) void scatter_kernel(
    const int* __restrict__ node_idx, const int* __restrict__ edge_idx,
    int* __restrict__ cur_v, int* __restrict__ cur_e,
    int* __restrict__ csrE_nodes, int* __restrict__ csrV_edges, int nnz)
{
    int k = blockIdx.x * 256 + threadIdx.x;
    if (k < nnz) {
        int v = node_idx[k], e = edge_idx[k];
        int p = atomicAdd(&cur_e[e], 1);
        csrE_nodes[p] = v;
        int q = atomicAdd(&cur_v[v], 1);
        csrV_edges[q] = e;
    }
}

// ---------------------------------------------------------------------------
// fp32 GEMM  Y[N,FOUT] = X[N,FIN] @ W[FIN,FOUT] + bias   (vector FMA; no fp32 MFMA)
// ---------------------------------------------------------------------------
template<int FIN, int FOUT>
__global__ __launch_bounds__(256) void gemm_bias(
    const float* __restrict__ X, const float* __restrict__ W,
    const float* __restrict__ Bias, float* __restrict__ Y, int N)
{
    constexpr int BR = 4096 / FOUT;
    constexpr int CG = FOUT / 4;
    constexpr int KB = 32;

    __shared__ float Xs[BR][KB + 1];
    __shared__ float Ws[KB][FOUT];

    const int tid  = threadIdx.x;
    const int cg   = tid % CG;
    const int rg   = tid / CG;
    const int row0 = blockIdx.x * BR;

    float acc[4][4];
    #pragma unroll
    for (int i = 0; i < 4; ++i)
        #pragma unroll
        for (int j = 0; j < 4; ++j) acc[i][j] = 0.f;

    for (int k0 = 0; k0 < FIN; k0 += KB) {
        #pragma unroll
        for (int t = tid; t < BR * KB; t += 256) {
            int r = t / KB, k = t % KB;
            int gr = row0 + r; if (gr >= N) gr = N - 1;
            Xs[r][k] = X[gr * FIN + k0 + k];
        }
        #pragma unroll
        for (int t = tid; t < KB * FOUT; t += 256) {
            int k = t / FOUT, c = t % FOUT;
            Ws[k][c] = W[(k0 + k) * FOUT + c];
        }
        __syncthreads();
        #pragma unroll
        for (int k = 0; k < KB; ++k) {
            float4 wv = *(const float4*)&Ws[k][cg * 4];
            float xv0 = Xs[rg * 4 + 0][k];
            float xv1 = Xs[rg * 4 + 1][k];
            float xv2 = Xs[rg * 4 + 2][k];
            float xv3 = Xs[rg * 4 + 3][k];
            acc[0][0] += xv0 * wv.x; acc[0][1] += xv0 * wv.y; acc[0][2] += xv0 * wv.z; acc[0][3] += xv0 * wv.w;
            acc[1][0] += xv1 * wv.x; acc[1][1] += xv1 * wv.y; acc[1][2] += xv1 * wv.z; acc[1][3] += xv1 * wv.w;
            acc[2][0] += xv2 * wv.x; acc[2][1] += xv2 * wv.y; acc[2][2] += xv2 * wv.z; acc[2][3] += xv2 * wv.w;
            acc[3][0] += xv3 * wv.x; acc[3][1] += xv3 * wv.y; acc[3][2] += xv3 * wv.z; acc[3][3] += xv3 * wv.w;
        }
        __syncthreads();
    }

    float4 bv = *(const float4*)&Bias[cg * 4];
    #pragma unroll
    for (int i = 0; i < 4; ++i) {
        int gr = row0 + rg * 4 + i;
        if (gr < N) {
            float4 o;
            o.x = acc[i][0] + bv.x; o.y = acc[i][1] + bv.y;
            o.z = acc[i][2] + bv.z; o.w = acc[i][3] + bv.w;
            *(float4*)&Y[gr * FOUT + cg * 4] = o;
        }
    }
}

// ---------------------------------------------------------------------------
// Wave-per-segment gather-sum. Segment id is wave-uniform (readfirstlane) so
// offs/lst loads scalarize (s_load, consecutive indices merge to dwordx4),
// leaving the vector pipe purely for row gathers. Unroll x4 -> 4 independent
// row gathers in flight per wave. Register accumulate, no LDS.
// ---------------------------------------------------------------------------

// F=128: lane covers cols [2*lane, 2*lane+1] via float2; 512B/row/instr.
template<bool RELU>
__global__ __launch_bounds__(256) void seg_gather_f128(
    const float* __restrict__ SRC, const int* __restrict__ offs,
    const int* __restrict__ lst, const float* __restrict__ inv,
    float* __restrict__ DST, int nseg)
{
    int s = blockIdx.x * 4 + (threadIdx.x >> 6);
    s = __builtin_amdgcn_readfirstlane(s);
    if (s >= nseg) return;
    const int lane = threadIdx.x & 63;
    int p   = offs[s];
    const int end = offs[s + 1];
    const float* srcl = SRC + lane * 2;
    float ax = 0.f, ay = 0.f;
    for (; p + 4 <= end; p += 4) {
        int r0 = lst[p], r1 = lst[p + 1], r2 = lst[p + 2], r3 = lst[p + 3];
        float2 a0 = *(const float2*)(srcl + (size_t)r0 * 128);
        float2 a1 = *(const float2*)(srcl + (size_t)r1 * 128);
        float2 a2 = *(const float2*)(srcl + (size_t)r2 * 128);
        float2 a3 = *(const float2*)(srcl + (size_t)r3 * 128);
        ax += a0.x + a1.x + a2.x + a3.x;
        ay += a0.y + a1.y + a2.y + a3.y;
    }
    for (; p < end; ++p) {
        int r = lst[p];
        float2 a = *(const float2*)(srcl + (size_t)r * 128);
        ax += a.x; ay += a.y;
    }
    float sc = inv[s];
    ax *= sc; ay *= sc;
    if (RELU) { ax = fmaxf(ax, 0.f); ay = fmaxf(ay, 0.f); }
    float2 o; o.x = ax; o.y = ay;
    *(float2*)(DST + (size_t)s * 128 + lane * 2) = o;
}

// F=64: half-wave trick — half h=lane>>5 takes neighbors p+h (stride 2),
// lane covers cols [2*c, 2*c+1] (c=lane&31) via float2; shfl_xor(32) combine.
template<bool RELU>
__global__ __launch_bounds__(256) void seg_gather_f64(
    const float* __restrict__ SRC, const int* __restrict__ offs,
    const int* __restrict__ lst, const float* __restrict__ inv,
    float* __restrict__ DST, int nseg)
{
    int s = blockIdx.x * 4 + (threadIdx.x >> 6);
    s = __builtin_amdgcn_readfirstlane(s);
    if (s >= nseg) return;
    const int lane = threadIdx.x & 63;
    const int h = lane >> 5, c = lane & 31;
    const int start = offs[s], end = offs[s + 1];
    const float* srcl = SRC + c * 2;
    float ax = 0.f, ay = 0.f;
    int p = start + h;
    for (; p + 6 < end; p += 8) {
        int r0 = lst[p], r1 = lst[p + 2], r2 = lst[p + 4], r3 = lst[p + 6];
        float2 a0 = *(const float2*)(srcl + (size_t)r0 * 64);
        float2 a1 = *(const float2*)(srcl + (size_t)r1 * 64);
        float2 a2 = *(const float2*)(srcl + (size_t)r2 * 64);
        float2 a3 = *(const float2*)(srcl + (size_t)r3 * 64);
        ax += a0.x + a1.x + a2.x + a3.x;
        ay += a0.y + a1.y + a2.y + a3.y;
    }
    for (; p < end; p += 2) {
        int r = lst[p];
        float2 a = *(const float2*)(srcl + (size_t)r * 64);
        ax += a.x; ay += a.y;
    }
    ax += __shfl_xor(ax, 32);
    ay += __shfl_xor(ay, 32);
    if (lane < 32) {
        float sc = inv[s];
        ax *= sc; ay *= sc;
        if (RELU) { ax = fmaxf(ax, 0.f); ay = fmaxf(ay, 0.f); }
        float2 o; o.x = ax; o.y = ay;
        *(float2*)(DST + (size_t)s * 64 + c * 2) = o;
    }
}

// F=32: half-wave trick, scalar float per lane (c=lane&31).
template<bool RELU>
__global__ __launch_bounds__(256) void seg_gather_f32(
    const float* __restrict__ SRC, const int* __restrict__ offs,
    const int* __restrict__ lst, const float* __restrict__ inv,
    float* __restrict__ DST, int nseg)
{
    int s = blockIdx.x * 4 + (threadIdx.x >> 6);
    s = __builtin_amdgcn_readfirstlane(s);
    if (s >= nseg) return;
    const int lane = threadIdx.x & 63;
    const int h = lane >> 5, c = lane & 31;
    const int start = offs[s], end = offs[s + 1];
    const float* srcl = SRC + c;
    float ax = 0.f;
    int p = start + h;
    for (; p + 6 < end; p += 8) {
        int r0 = lst[p], r1 = lst[p + 2], r2 = lst[p + 4], r3 = lst[p + 6];
        ax += srcl[(size_t)r0 * 32] + srcl[(size_t)r1 * 32]
            + srcl[(size_t)r2 * 32] + srcl[(size_t)r3 * 32];
    }
    for (; p < end; p += 2) {
        ax += srcl[(size_t)lst[p] * 32];
    }
    ax += __shfl_xor(ax, 32);
    if (lane < 32) {
        float o = ax * inv[s];
        if (RELU) o = fmaxf(o, 0.f);
        DST[(size_t)s * 32 + c] = o;
    }
}

// ---------------------------------------------------------------------------
extern "C" void kernel_launch(void* const* d_in, const int* in_sizes, int n_in,
                              void* d_out, int out_size, void* d_ws, size_t ws_size,
                              hipStream_t stream)
{
    const float* x  = (const float*)d_in[0];
    const int* edge = (const int*)d_in[1];
    const float* w1 = (const float*)d_in[2];
    const float* b1 = (const float*)d_in[3];
    const float* w2 = (const float*)d_in[4];
    const float* b2 = (const float*)d_in[5];
    const float* w3 = (const float*)d_in[6];
    const float* b3 = (const float*)d_in[7];
    float* out = (float*)d_out;

    const int N = N_NODES, E = N_EDGES, NNZ = NNZ_TOT;
    const int* node_idx = edge;
    const int* edge_idx = edge + NNZ;

    uintptr_t base = (uintptr_t)d_ws;
    size_t off = 0;
    auto take = [&](size_t nbytes) -> void* {
        off = (off + 255) & ~(size_t)255;
        void* p = (void*)(base + off);
        off += nbytes;
        return p;
    };
    int*   cur_e  = (int*)  take((size_t)E * 4);
    int*   cur_v  = (int*)  take((size_t)N * 4);
    int*   offs_e = (int*)  take((size_t)(E + 1) * 4);
    int*   offs_v = (int*)  take((size_t)(N + 1) * 4);
    float* Binv   = (float*)take((size_t)E * 4);
    float* Dinv   = (float*)take((size_t)N * 4);
    int*   csrE   = (int*)  take((size_t)NNZ * 4);
    int*   csrV   = (int*)  take((size_t)NNZ * 4);
    float* xw     = (float*)take((size_t)N * 128 * 4);
    float* hA     = (float*)take((size_t)N * 128 * 4);
    float* hB     = (float*)take((size_t)N * 64 * 4);
    float* me     = (float*)take((size_t)E * 128 * 4);

    hipMemsetAsync(cur_e, 0, (size_t)E * 4, stream);
    hipMemsetAsync(cur_v, 0, (size_t)N * 4, stream);

    hist_kernel<<<(NNZ + 255) / 256, 256, 0, stream>>>(node_idx, edge_idx, cur_v, cur_e, NNZ);
    scan_kernel<<<2, 1024, 0, stream>>>(cur_e, offs_e, Binv, E, cur_v, offs_v, Dinv, N);
    scatter_kernel<<<(NNZ + 255) / 256, 256, 0, stream>>>(node_idx, edge_idx, cur_v, cur_e, csrE, csrV, NNZ);

    // Layer 1: 128 -> 128
    gemm_bias<128, 128><<<(N + 31) / 32, 256, 0, stream>>>(x, w1, b1, xw, N);
    seg_gather_f128<false><<<(E + 3) / 4, 256, 0, stream>>>(xw, offs_e, csrE, Binv, me, E);
    seg_gather_f128<true ><<<(N + 3) / 4, 256, 0, stream>>>(me, offs_v, csrV, Dinv, hA, N);

    // Layer 2: 128 -> 64
    gemm_bias<128, 64><<<(N + 63) / 64, 256, 0, stream>>>(hA, w2, b2, xw, N);
    seg_gather_f64<false><<<(E + 3) / 4, 256, 0, stream>>>(xw, offs_e, csrE, Binv, me, E);
    seg_gather_f64<true ><<<(N + 3) / 4, 256, 0, stream>>>(me, offs_v, csrV, Dinv, hB, N);

    // Layer 3: 64 -> 32
    gemm_bias<64, 32><<<(N + 127) / 128, 256, 0, stream>>>(hB, w3, b3, xw, N);
    seg_gather_f32<false><<<(E + 3) / 4, 256, 0, stream>>>(xw, offs_e, csrE, Binv, me, E);
    seg_gather_f32<true ><<<(N + 3) / 4, 256, 0, stream>>>(me, offs_v, csrV, Dinv, out, N);
}

// Round 3
// 474.861 us; speedup vs baseline: 1.6176x; 1.1761x over previous
//
#include <hip/hip_runtime.h>

#define N_NODES   50000
#define N_EDGES   10000
#define NNZ_TOT   800000

// Bucketing geometry for the two-phase CSR build
#define SW_E 16                      // edges per E-bucket
#define NB_E 625                     // 10000/16
#define SW_V 64                      // nodes per V-bucket
#define NB_V 782                     // ceil(50000/64)

// ---------------------------------------------------------------------------
// Histogram: count node / hyperedge degrees
// ---------------------------------------------------------------------------
__global__ __launch_bounds__(256) void hist_kernel(
    const int* __restrict__ node_idx, const int* __restrict__ edge_idx,
    int* __restrict__ cnt_v, int* __restrict__ cnt_e, int nnz)
{
    int k = blockIdx.x * 256 + threadIdx.x;
    if (k < nnz) {
        atomicAdd(&cnt_v[node_idx[k]], 1);
        atomicAdd(&cnt_e[edge_idx[k]], 1);
    }
}

// ---------------------------------------------------------------------------
// Exclusive prefix sum over degree arrays (block 0: edges, block 1: nodes).
// Writes offs[i], inv[i]=1/deg, and seeds the global bucket cursors
// (curB[b] = offs[b*SW]) used by bucketize_kernel's reservations.
// ---------------------------------------------------------------------------
__global__ __launch_bounds__(1024) void scan_kernel(
    int* __restrict__ cnt_e, int* __restrict__ offs_e, float* __restrict__ Binv,
    int* __restrict__ curBE,
    int* __restrict__ cnt_v, int* __restrict__ offs_v, float* __restrict__ Dinv,
    int* __restrict__ curBV)
{
    int* cnt; int* offs; float* inv; int n; int* curB; int nb, sw;
    if (blockIdx.x == 0) { cnt = cnt_e; offs = offs_e; inv = Binv; n = N_EDGES; curB = curBE; nb = NB_E; sw = SW_E; }
    else                 { cnt = cnt_v; offs = offs_v; inv = Dinv; n = N_NODES; curB = curBV; nb = NB_V; sw = SW_V; }

    __shared__ int wtot[16];
    __shared__ int s_run;
    const int tid  = threadIdx.x;
    const int lane = tid & 63;
    const int w    = tid >> 6;
    if (tid == 0) s_run = 0;
    __syncthreads();

    for (int base = 0; base < n; base += 1024) {
        int i   = base + tid;
        int val = (i < n) ? cnt[i] : 0;

        int x = val;
        #pragma unroll
        for (int d = 1; d < 64; d <<= 1) {
            int y = __shfl_up(x, d, 64);
            if (lane >= d) x += y;
        }
        if (lane == 63) wtot[w] = x;
        __syncthreads();
        if (w == 0) {
            int t = (lane < 16) ? wtot[lane] : 0;
            #pragma unroll
            for (int d = 1; d < 16; d <<= 1) {
                int y = __shfl_up(t, d, 64);
                if (lane >= d) t += y;
            }
            if (lane < 16) wtot[lane] = t;
        }
        __syncthreads();
        int incl = x + ((w > 0) ? wtot[w - 1] : 0);
        int excl = incl - val;
        int run  = s_run;
        if (i < n) {
            int o   = run + excl;
            offs[i] = o;
            inv[i]  = (val > 0) ? (1.0f / (float)val) : 0.0f;
        }
        __syncthreads();
        if (tid == 1023) s_run = run + incl;
        __syncthreads();
    }
    if (tid == 0) offs[n] = s_run;
    __syncthreads();
    // seed bucket cursors with bucket base offsets (b*sw < n always holds)
    for (int b = tid; b < nb; b += 1024) curB[b] = offs[b * sw];
}

// ---------------------------------------------------------------------------
// Phase 1: bucket-sort incidences by coarse key range, both directions.
// Per-block LDS histogram -> one global reservation atomic per (block,bucket)
// -> contiguous per-block runs inside each bucket slice (coalesced-ish writes,
// single-XCD line ownership: no 64B-per-4B writeback amplification).
// Pack: (key<<16)|payload; key=e (<16384) or v (<65536), payload fits 16 bits.
// ---------------------------------------------------------------------------
__global__ __launch_bounds__(1024) void bucketize_kernel(
    const int* __restrict__ node_idx, const int* __restrict__ edge_idx,
    int* __restrict__ curBE, int* __restrict__ curBV,
    unsigned int* __restrict__ bktE, unsigned int* __restrict__ bktV, int nnz)
{
    __shared__ int hE[NB_E];
    __shared__ int hV[NB_V];
    const int tid = threadIdx.x;
    for (int t = tid; t < NB_E; t += 1024) hE[t] = 0;
    for (int t = tid; t < NB_V; t += 1024) hV[t] = 0;
    __syncthreads();

    unsigned int pE[16], pV[16];
    const int base = blockIdx.x * 16384;
    #pragma unroll
    for (int j = 0; j < 16; ++j) {
        int k = base + j * 1024 + tid;
        if (k < nnz) {
            unsigned int v = (unsigned int)node_idx[k];
            unsigned int e = (unsigned int)edge_idx[k];
            pE[j] = (e << 16) | v;
            pV[j] = (v << 16) | e;
            atomicAdd(&hE[e >> 4], 1);
            atomicAdd(&hV[v >> 6], 1);
        } else { pE[j] = 0xFFFFFFFFu; pV[j] = 0xFFFFFFFFu; }
    }
    __syncthreads();
    // reserve per-block ranges inside each bucket; hX[t] becomes local cursor
    for (int t = tid; t < NB_E; t += 1024) {
        int c = hE[t];
        hE[t] = c ? atomicAdd(&curBE[t], c) : 0;
    }
    for (int t = tid; t < NB_V; t += 1024) {
        int c = hV[t];
        hV[t] = c ? atomicAdd(&curBV[t], c) : 0;
    }
    __syncthreads();
    #pragma unroll
    for (int j = 0; j < 16; ++j) {
        if (pE[j] != 0xFFFFFFFFu) {
            int se = atomicAdd(&hE[pE[j] >> 20], 1);   // pack>>20 == e>>4
            bktE[se] = pE[j];
            int sv = atomicAdd(&hV[pV[j] >> 22], 1);   // pack>>22 == v>>6
            bktV[sv] = pV[j];
        }
    }
}

// ---------------------------------------------------------------------------
// Phase 2: one block per bucket finalizes the CSR adjacency. Ranks via LDS
// cursors (zero global atomics); writes confined to the bucket's private
// ~5KB CSR window -> L1/L2-local, written back once.
// Grid = NB_E + NB_V (E buckets first).
// ---------------------------------------------------------------------------
__global__ __launch_bounds__(256) void csr_build_kernel(
    const unsigned int* __restrict__ bktE, const unsigned int* __restrict__ bktV,
    const int* __restrict__ offs_e, const int* __restrict__ offs_v,
    int* __restrict__ csrE, int* __restrict__ csrV)
{
    __shared__ int cur[SW_V];
    int b = blockIdx.x;
    const unsigned int* bkt; const int* offs; int* csr; int lo, sw, nseg;
    if (b < NB_E) { bkt = bktE; offs = offs_e; csr = csrE; sw = SW_E; lo = b * SW_E; nseg = N_EDGES; }
    else { b -= NB_E; bkt = bktV; offs = offs_v; csr = csrV; sw = SW_V; lo = b * SW_V; nseg = N_NODES; }
    int hi = lo + sw; if (hi > nseg) hi = nseg;
    int ns = hi - lo;
    if (threadIdx.x < ns) cur[threadIdx.x] = offs[lo + threadIdx.x];
    __syncthreads();
    const int p0 = offs[lo], p1 = offs[hi];
    for (int p = p0 + threadIdx.x; p < p1; p += 256) {
        unsigned int pk = bkt[p];
        int key = (int)(pk >> 16);
        int pay = (int)(pk & 0xFFFFu);
        int slot = atomicAdd(&cur[key - lo], 1);
        csr[slot] = pay;
    }
}

// ---------------------------------------------------------------------------
// fp32 GEMM  Y[N,FOUT] = X[N,FIN] @ W[FIN,FOUT] + bias   (vector FMA; no fp32 MFMA)
// ---------------------------------------------------------------------------
template<int FIN, int FOUT>
__global__ __launch_bounds__(256) void gemm_bias(
    const float* __restrict__ X, const float* __restrict__ W,
    const float* __restrict__ Bias, float* __restrict__ Y, int N)
{
    constexpr int BR = 4096 / FOUT;
    constexpr int CG = FOUT / 4;
    constexpr int KB = 32;

    __shared__ float Xs[BR][KB + 1];
    __shared__ float Ws[KB][FOUT];

    const int tid  = threadIdx.x;
    const int cg   = tid % CG;
    const int rg   = tid / CG;
    const int row0 = blockIdx.x * BR;

    float acc[4][4];
    #pragma unroll
    for (int i = 0; i < 4; ++i)
        #pragma unroll
        for (int j = 0; j < 4; ++j) acc[i][j] = 0.f;

    for (int k0 = 0; k0 < FIN; k0 += KB) {
        #pragma unroll
        for (int t = tid; t < BR * KB; t += 256) {
            int r = t / KB, k = t % KB;
            int gr = row0 + r; if (gr >= N) gr = N - 1;
            Xs[r][k] = X[gr * FIN + k0 + k];
        }
        #pragma unroll
        for (int t = tid; t < KB * FOUT; t += 256) {
            int k = t / FOUT, c = t % FOUT;
            Ws[k][c] = W[(k0 + k) * FOUT + c];
        }
        __syncthreads();
        #pragma unroll
        for (int k = 0; k < KB; ++k) {
            float4 wv = *(const float4*)&Ws[k][cg * 4];
            float xv0 = Xs[rg * 4 + 0][k];
            float xv1 = Xs[rg * 4 + 1][k];
            float xv2 = Xs[rg * 4 + 2][k];
            float xv3 = Xs[rg * 4 + 3][k];
            acc[0][0] += xv0 * wv.x; acc[0][1] += xv0 * wv.y; acc[0][2] += xv0 * wv.z; acc[0][3] += xv0 * wv.w;
            acc[1][0] += xv1 * wv.x; acc[1][1] += xv1 * wv.y; acc[1][2] += xv1 * wv.z; acc[1][3] += xv1 * wv.w;
            acc[2][0] += xv2 * wv.x; acc[2][1] += xv2 * wv.y; acc[2][2] += xv2 * wv.z; acc[2][3] += xv2 * wv.w;
            acc[3][0] += xv3 * wv.x; acc[3][1] += xv3 * wv.y; acc[3][2] += xv3 * wv.z; acc[3][3] += xv3 * wv.w;
        }
        __syncthreads();
    }

    float4 bv = *(const float4*)&Bias[cg * 4];
    #pragma unroll
    for (int i = 0; i < 4; ++i) {
        int gr = row0 + rg * 4 + i;
        if (gr < N) {
            float4 o;
            o.x = acc[i][0] + bv.x; o.y = acc[i][1] + bv.y;
            o.z = acc[i][2] + bv.z; o.w = acc[i][3] + bv.w;
            *(float4*)&Y[gr * FOUT + cg * 4] = o;
        }
    }
}

// ---------------------------------------------------------------------------
// Wave-per-segment gather-sum (segment id wave-uniform -> scalar offs/lst
// loads; unroll x4 keeps 4 row gathers in flight; register accumulate).
// ---------------------------------------------------------------------------
template<bool RELU>
__global__ __launch_bounds__(256) void seg_gather_f128(
    const float* __restrict__ SRC, const int* __restrict__ offs,
    const int* __restrict__ lst, const float* __restrict__ inv,
    float* __restrict__ DST, int nseg)
{
    int s = blockIdx.x * 4 + (threadIdx.x >> 6);
    s = __builtin_amdgcn_readfirstlane(s);
    if (s >= nseg) return;
    const int lane = threadIdx.x & 63;
    int p   = offs[s];
    const int end = offs[s + 1];
    const float* srcl = SRC + lane * 2;
    float ax = 0.f, ay = 0.f;
    for (; p + 4 <= end; p += 4) {
        int r0 = lst[p], r1 = lst[p + 1], r2 = lst[p + 2], r3 = lst[p + 3];
        float2 a0 = *(const float2*)(srcl + (size_t)r0 * 128);
        float2 a1 = *(const float2*)(srcl + (size_t)r1 * 128);
        float2 a2 = *(const float2*)(srcl + (size_t)r2 * 128);
        float2 a3 = *(const float2*)(srcl + (size_t)r3 * 128);
        ax += a0.x + a1.x + a2.x + a3.x;
        ay += a0.y + a1.y + a2.y + a3.y;
    }
    for (; p < end; ++p) {
        int r = lst[p];
        float2 a = *(const float2*)(srcl + (size_t)r * 128);
        ax += a.x; ay += a.y;
    }
    float sc = inv[s];
    ax *= sc; ay *= sc;
    if (RELU) { ax = fmaxf(ax, 0.f); ay = fmaxf(ay, 0.f); }
    float2 o; o.x = ax; o.y = ay;
    *(float2*)(DST + (size_t)s * 128 + lane * 2) = o;
}

template<bool RELU>
__global__ __launch_bounds__(256) void seg_gather_f64(
    const float* __restrict__ SRC, const int* __restrict__ offs,
    const int* __restrict__ lst, const float* __restrict__ inv,
    float* __restrict__ DST, int nseg)
{
    int s = blockIdx.x * 4 + (threadIdx.x >> 6);
    s = __builtin_amdgcn_readfirstlane(s);
    if (s >= nseg) return;
    const int lane = threadIdx.x & 63;
    const int h = lane >> 5, c = lane & 31;
    const int start = offs[s], end = offs[s + 1];
    const float* srcl = SRC + c * 2;
    float ax = 0.f, ay = 0.f;
    int p = start + h;
    for (; p + 6 < end; p += 8) {
        int r0 = lst[p], r1 = lst[p + 2], r2 = lst[p + 4], r3 = lst[p + 6];
        float2 a0 = *(const float2*)(srcl + (size_t)r0 * 64);
        float2 a1 = *(const float2*)(srcl + (size_t)r1 * 64);
        float2 a2 = *(const float2*)(srcl + (size_t)r2 * 64);
        float2 a3 = *(const float2*)(srcl + (size_t)r3 * 64);
        ax += a0.x + a1.x + a2.x + a3.x;
        ay += a0.y + a1.y + a2.y + a3.y;
    }
    for (; p < end; p += 2) {
        int r = lst[p];
        float2 a = *(const float2*)(srcl + (size_t)r * 64);
        ax += a.x; ay += a.y;
    }
    ax += __shfl_xor(ax, 32);
    ay += __shfl_xor(ay, 32);
    if (lane < 32) {
        float sc = inv[s];
        ax *= sc; ay *= sc;
        if (RELU) { ax = fmaxf(ax, 0.f); ay = fmaxf(ay, 0.f); }
        float2 o; o.x = ax; o.y = ay;
        *(float2*)(DST + (size_t)s * 64 + c * 2) = o;
    }
}

template<bool RELU>
__global__ __launch_bounds__(256) void seg_gather_f32(
    const float* __restrict__ SRC, const int* __restrict__ offs,
    const int* __restrict__ lst, const float* __restrict__ inv,
    float* __restrict__ DST, int nseg)
{
    int s = blockIdx.x * 4 + (threadIdx.x >> 6);
    s = __builtin_amdgcn_readfirstlane(s);
    if (s >= nseg) return;
    const int lane = threadIdx.x & 63;
    const int h = lane >> 5, c = lane & 31;
    const int start = offs[s], end = offs[s + 1];
    const float* srcl = SRC + c;
    float ax = 0.f;
    int p = start + h;
    for (; p + 6 < end; p += 8) {
        int r0 = lst[p], r1 = lst[p + 2], r2 = lst[p + 4], r3 = lst[p + 6];
        ax += srcl[(size_t)r0 * 32] + srcl[(size_t)r1 * 32]
            + srcl[(size_t)r2 * 32] + srcl[(size_t)r3 * 32];
    }
    for (; p < end; p += 2) {
        ax += srcl[(size_t)lst[p] * 32];
    }
    ax += __shfl_xor(ax, 32);
    if (lane < 32) {
        float o = ax * inv[s];
        if (RELU) o = fmaxf(o, 0.f);
        DST[(size_t)s * 32 + c] = o;
    }
}

// ---------------------------------------------------------------------------
extern "C" void kernel_launch(void* const* d_in, const int* in_sizes, int n_in,
                              void* d_out, int out_size, void* d_ws, size_t ws_size,
                              hipStream_t stream)
{
    const float* x  = (const float*)d_in[0];
    const int* edge = (const int*)d_in[1];
    const float* w1 = (const float*)d_in[2];
    const float* b1 = (const float*)d_in[3];
    const float* w2 = (const float*)d_in[4];
    const float* b2 = (const float*)d_in[5];
    const float* w3 = (const float*)d_in[6];
    const float* b3 = (const float*)d_in[7];
    float* out = (float*)d_out;

    const int N = N_NODES, E = N_EDGES, NNZ = NNZ_TOT;
    const int* node_idx = edge;
    const int* edge_idx = edge + NNZ;

    uintptr_t base = (uintptr_t)d_ws;
    size_t off = 0;
    auto take = [&](size_t nbytes) -> void* {
        off = (off + 255) & ~(size_t)255;
        void* p = (void*)(base + off);
        off += nbytes;
        return p;
    };
    int*   cnt_e  = (int*)  take((size_t)E * 4);
    int*   cnt_v  = (int*)  take((size_t)N * 4);
    int*   offs_e = (int*)  take((size_t)(E + 1) * 4);
    int*   offs_v = (int*)  take((size_t)(N + 1) * 4);
    float* Binv   = (float*)take((size_t)E * 4);
    float* Dinv   = (float*)take((size_t)N * 4);
    int*   curBE  = (int*)  take((size_t)NB_E * 4);
    int*   curBV  = (int*)  take((size_t)NB_V * 4);
    int*   csrE   = (int*)  take((size_t)NNZ * 4);
    int*   csrV   = (int*)  take((size_t)NNZ * 4);
    float* xw     = (float*)take((size_t)N * 128 * 4);
    float* hA     = (float*)take((size_t)N * 128 * 4);
    float* hB     = (float*)take((size_t)N * 64 * 4);
    float* me     = (float*)take((size_t)E * 128 * 4);

    // bucket arrays alias hA: dead until the layer-1 node gather, long after
    // csr_build consumes them (single stream, sequential dependencies)
    unsigned int* bktE = (unsigned int*)hA;
    unsigned int* bktV = bktE + NNZ;

    hipMemsetAsync(cnt_e, 0, (size_t)E * 4, stream);
    hipMemsetAsync(cnt_v, 0, (size_t)N * 4, stream);

    hist_kernel<<<(NNZ + 255) / 256, 256, 0, stream>>>(node_idx, edge_idx, cnt_v, cnt_e, NNZ);
    scan_kernel<<<2, 1024, 0, stream>>>(cnt_e, offs_e, Binv, curBE, cnt_v, offs_v, Dinv, curBV);
    bucketize_kernel<<<(NNZ + 16383) / 16384, 1024, 0, stream>>>(
        node_idx, edge_idx, curBE, curBV, bktE, bktV, NNZ);
    csr_build_kernel<<<NB_E + NB_V, 256, 0, stream>>>(bktE, bktV, offs_e, offs_v, csrE, csrV);

    // Layer 1: 128 -> 128
    gemm_bias<128, 128><<<(N + 31) / 32, 256, 0, stream>>>(x, w1, b1, xw, N);
    seg_gather_f128<false><<<(E + 3) / 4, 256, 0, stream>>>(xw, offs_e, csrE, Binv, me, E);
    seg_gather_f128<true ><<<(N + 3) / 4, 256, 0, stream>>>(me, offs_v, csrV, Dinv, hA, N);

    // Layer 2: 128 -> 64
    gemm_bias<128, 64><<<(N + 63) / 64, 256, 0, stream>>>(hA, w2, b2, xw, N);
    seg_gather_f64<false><<<(E + 3) / 4, 256, 0, stream>>>(xw, offs_e, csrE, Binv, me, E);
    seg_gather_f64<true ><<<(N + 3) / 4, 256, 0, stream>>>(me, offs_v, csrV, Dinv, hB, N);

    // Layer 3: 64 -> 32
    gemm_bias<64, 32><<<(N + 127) / 128, 256, 0, stream>>>(hB, w3, b3, xw, N);
    seg_gather_f32<false><<<(E + 3) / 4, 256, 0, stream>>>(xw, offs_e, csrE, Binv, me, E);
    seg_gather_f32<true ><<<(N + 3) / 4, 256, 0, stream>>>(me, offs_v, csrV, Dinv, out, N);
}

// Round 4
// 365.073 us; speedup vs baseline: 2.1041x; 1.3007x over previous
//
#include <hip/hip_runtime.h>

#define N_NODES   50000
#define N_EDGES   10000
#define NNZ_TOT   800000

// Bucketing geometry for the two-phase CSR build
#define SW_E 16                      // edges per E-bucket
#define NB_E 625                     // 10000/16
#define SW_V 64                      // nodes per V-bucket
#define NB_V 782                     // ceil(50000/64)

// ---------------------------------------------------------------------------
// Step 1: coarse bucket counts. LDS histograms (625+782 counters), then ONE
// global atomic per (block,bucket): ~69k atomics on a 5.6KB table instead of
// 1.6M fine atomics on 240KB (the old hist_kernel's 49MB write storm).
// ---------------------------------------------------------------------------
__global__ __launch_bounds__(1024) void bucket_count_kernel(
    const int* __restrict__ node_idx, const int* __restrict__ edge_idx,
    int* __restrict__ cntBE, int* __restrict__ cntBV, int nnz)
{
    __shared__ int hE[NB_E];
    __shared__ int hV[NB_V];
    const int tid = threadIdx.x;
    for (int t = tid; t < NB_E; t += 1024) hE[t] = 0;
    for (int t = tid; t < NB_V; t += 1024) hV[t] = 0;
    __syncthreads();

    const int base = blockIdx.x * 16384;
    #pragma unroll
    for (int j = 0; j < 16; ++j) {
        int k = base + j * 1024 + tid;
        if (k < nnz) {
            unsigned int v = (unsigned int)node_idx[k];
            unsigned int e = (unsigned int)edge_idx[k];
            atomicAdd(&hE[e >> 4], 1);
            atomicAdd(&hV[v >> 6], 1);
        }
    }
    __syncthreads();
    for (int t = tid; t < NB_E; t += 1024) { int c = hE[t]; if (c) atomicAdd(&cntBE[t], c); }
    for (int t = tid; t < NB_V; t += 1024) { int c = hV[t]; if (c) atomicAdd(&cntBV[t], c); }
}

// ---------------------------------------------------------------------------
// Step 2: exclusive scan of bucket counts -> bucket bases (bktOff) and the
// global scatter cursors (curB). Block 0: E (625), block 1: V (782); both fit
// one 1024-thread chunk. Also writes offs[n]=NNZ terminators.
// ---------------------------------------------------------------------------
__global__ __launch_bounds__(1024) void bucket_scan_kernel(
    const int* __restrict__ cntBE, int* __restrict__ bktOffE, int* __restrict__ curBE,
    int* __restrict__ offs_e,
    const int* __restrict__ cntBV, int* __restrict__ bktOffV, int* __restrict__ curBV,
    int* __restrict__ offs_v)
{
    const int* cnt; int* bktOff; int* curB; int nb;
    if (blockIdx.x == 0) {
        cnt = cntBE; bktOff = bktOffE; curB = curBE; nb = NB_E;
        if (threadIdx.x == 0) offs_e[N_EDGES] = NNZ_TOT;
    } else {
        cnt = cntBV; bktOff = bktOffV; curB = curBV; nb = NB_V;
        if (threadIdx.x == 0) offs_v[N_NODES] = NNZ_TOT;
    }

    __shared__ int wtot[16];
    const int tid  = threadIdx.x;
    const int lane = tid & 63;
    const int w    = tid >> 6;

    int val = (tid < nb) ? cnt[tid] : 0;
    int x = val;
    #pragma unroll
    for (int d = 1; d < 64; d <<= 1) {
        int y = __shfl_up(x, d, 64);
        if (lane >= d) x += y;
    }
    if (lane == 63) wtot[w] = x;
    __syncthreads();
    if (w == 0) {
        int t = (lane < 16) ? wtot[lane] : 0;
        #pragma unroll
        for (int d = 1; d < 16; d <<= 1) {
            int y = __shfl_up(t, d, 64);
            if (lane >= d) t += y;
        }
        if (lane < 16) wtot[lane] = t;
    }
    __syncthreads();
    int incl = x + ((w > 0) ? wtot[w - 1] : 0);
    int excl = incl - val;
    if (tid < nb) {
        bktOff[tid] = excl;
        curB[tid]   = excl;
    }
    if (tid == 0) bktOff[nb] = NNZ_TOT;
}

// ---------------------------------------------------------------------------
// Step 3: bucket-sort incidences, both directions. Per-block LDS histogram ->
// one reservation atomic per (block,bucket) -> contiguous per-block runs in
// each bucket slice (single-owner lines: no 64B-per-4B writeback blowup).
// Pack: (key<<16)|payload; e<16384, v<65536 both fit.
// ---------------------------------------------------------------------------
__global__ __launch_bounds__(1024) void bucket_write_kernel(
    const int* __restrict__ node_idx, const int* __restrict__ edge_idx,
    int* __restrict__ curBE, int* __restrict__ curBV,
    unsigned int* __restrict__ bktE, unsigned int* __restrict__ bktV, int nnz)
{
    __shared__ int hE[NB_E];
    __shared__ int hV[NB_V];
    const int tid = threadIdx.x;
    for (int t = tid; t < NB_E; t += 1024) hE[t] = 0;
    for (int t = tid; t < NB_V; t += 1024) hV[t] = 0;
    __syncthreads();

    unsigned int pE[16], pV[16];
    const int base = blockIdx.x * 16384;
    #pragma unroll
    for (int j = 0; j < 16; ++j) {
        int k = base + j * 1024 + tid;
        if (k < nnz) {
            unsigned int v = (unsigned int)node_idx[k];
            unsigned int e = (unsigned int)edge_idx[k];
            pE[j] = (e << 16) | v;
            pV[j] = (v << 16) | e;
            atomicAdd(&hE[e >> 4], 1);
            atomicAdd(&hV[v >> 6], 1);
        } else { pE[j] = 0xFFFFFFFFu; pV[j] = 0xFFFFFFFFu; }
    }
    __syncthreads();
    for (int t = tid; t < NB_E; t += 1024) {
        int c = hE[t];
        hE[t] = c ? atomicAdd(&curBE[t], c) : 0;
    }
    for (int t = tid; t < NB_V; t += 1024) {
        int c = hV[t];
        hV[t] = c ? atomicAdd(&curBV[t], c) : 0;
    }
    __syncthreads();
    #pragma unroll
    for (int j = 0; j < 16; ++j) {
        if (pE[j] != 0xFFFFFFFFu) {
            int se = atomicAdd(&hE[pE[j] >> 20], 1);   // pack>>20 == e>>4
            bktE[se] = pE[j];
            int sv = atomicAdd(&hV[pV[j] >> 22], 1);   // pack>>22 == v>>6
            bktV[sv] = pV[j];
        }
    }
}

// ---------------------------------------------------------------------------
// Step 4: one block per bucket. Pass 1: fine per-key LDS counts. One wave-scan
// (ns<=64) -> offs[i]=p0+excl, inv[i]=1/deg, LDS cursors. Pass 2: rank via
// LDS atomics, write CSR payload. Zero global atomics; slice is L2-hot.
// Grid = NB_E + NB_V (E buckets first).
// ---------------------------------------------------------------------------
__global__ __launch_bounds__(256) void csr_finalize_kernel(
    const unsigned int* __restrict__ bktE, const unsigned int* __restrict__ bktV,
    const int* __restrict__ bktOffE, const int* __restrict__ bktOffV,
    int* __restrict__ offs_e, int* __restrict__ offs_v,
    float* __restrict__ Binv, float* __restrict__ Dinv,
    int* __restrict__ csrE, int* __restrict__ csrV)
{
    __shared__ int cnt[SW_V];
    __shared__ int cur[SW_V];
    int b = blockIdx.x;
    const unsigned int* bkt; const int* bktOff; int* offs; float* inv; int* csr;
    int lo, sw, nseg;
    if (b < NB_E) {
        bkt = bktE; bktOff = bktOffE; offs = offs_e; inv = Binv; csr = csrE;
        sw = SW_E; lo = b * SW_E; nseg = N_EDGES;
    } else {
        b -= NB_E;
        bkt = bktV; bktOff = bktOffV; offs = offs_v; inv = Dinv; csr = csrV;
        sw = SW_V; lo = b * SW_V; nseg = N_NODES;
    }
    int hi = lo + sw; if (hi > nseg) hi = nseg;
    const int ns = hi - lo;
    const int p0 = bktOff[b], p1 = bktOff[b + 1];

    if (threadIdx.x < ns) cnt[threadIdx.x] = 0;
    __syncthreads();
    for (int p = p0 + threadIdx.x; p < p1; p += 256) {
        int key = (int)(bkt[p] >> 16);
        atomicAdd(&cnt[key - lo], 1);
    }
    __syncthreads();
    if (threadIdx.x < 64) {                 // single wave: scan ns<=64 counts
        int lane = threadIdx.x;
        int val = (lane < ns) ? cnt[lane] : 0;
        int x = val;
        #pragma unroll
        for (int d = 1; d < 64; d <<= 1) {
            int y = __shfl_up(x, d, 64);
            if (lane >= d) x += y;
        }
        int excl = x - val;
        if (lane < ns) {
            offs[lo + lane] = p0 + excl;
            inv[lo + lane]  = (val > 0) ? (1.0f / (float)val) : 0.0f;
            cur[lane]       = p0 + excl;
        }
    }
    __syncthreads();
    for (int p = p0 + threadIdx.x; p < p1; p += 256) {
        unsigned int pk = bkt[p];
        int key  = (int)(pk >> 16);
        int slot = atomicAdd(&cur[key - lo], 1);
        csr[slot] = (int)(pk & 0xFFFFu);
    }
}

// ---------------------------------------------------------------------------
// fp32 GEMM  Y[N,FOUT] = X[N,FIN] @ W[FIN,FOUT] + bias   (vector FMA; no fp32 MFMA)
// ---------------------------------------------------------------------------
template<int FIN, int FOUT>
__global__ __launch_bounds__(256) void gemm_bias(
    const float* __restrict__ X, const float* __restrict__ W,
    const float* __restrict__ Bias, float* __restrict__ Y, int N)
{
    constexpr int BR = 4096 / FOUT;
    constexpr int CG = FOUT / 4;
    constexpr int KB = 32;

    __shared__ float Xs[BR][KB + 1];
    __shared__ float Ws[KB][FOUT];

    const int tid  = threadIdx.x;
    const int cg   = tid % CG;
    const int rg   = tid / CG;
    const int row0 = blockIdx.x * BR;

    float acc[4][4];
    #pragma unroll
    for (int i = 0; i < 4; ++i)
        #pragma unroll
        for (int j = 0; j < 4; ++j) acc[i][j] = 0.f;

    for (int k0 = 0; k0 < FIN; k0 += KB) {
        #pragma unroll
        for (int t = tid; t < BR * KB; t += 256) {
            int r = t / KB, k = t % KB;
            int gr = row0 + r; if (gr >= N) gr = N - 1;
            Xs[r][k] = X[gr * FIN + k0 + k];
        }
        #pragma unroll
        for (int t = tid; t < KB * FOUT; t += 256) {
            int k = t / FOUT, c = t % FOUT;
            Ws[k][c] = W[(k0 + k) * FOUT + c];
        }
        __syncthreads();
        #pragma unroll
        for (int k = 0; k < KB; ++k) {
            float4 wv = *(const float4*)&Ws[k][cg * 4];
            float xv0 = Xs[rg * 4 + 0][k];
            float xv1 = Xs[rg * 4 + 1][k];
            float xv2 = Xs[rg * 4 + 2][k];
            float xv3 = Xs[rg * 4 + 3][k];
            acc[0][0] += xv0 * wv.x; acc[0][1] += xv0 * wv.y; acc[0][2] += xv0 * wv.z; acc[0][3] += xv0 * wv.w;
            acc[1][0] += xv1 * wv.x; acc[1][1] += xv1 * wv.y; acc[1][2] += xv1 * wv.z; acc[1][3] += xv1 * wv.w;
            acc[2][0] += xv2 * wv.x; acc[2][1] += xv2 * wv.y; acc[2][2] += xv2 * wv.z; acc[2][3] += xv2 * wv.w;
            acc[3][0] += xv3 * wv.x; acc[3][1] += xv3 * wv.y; acc[3][2] += xv3 * wv.z; acc[3][3] += xv3 * wv.w;
        }
        __syncthreads();
    }

    float4 bv = *(const float4*)&Bias[cg * 4];
    #pragma unroll
    for (int i = 0; i < 4; ++i) {
        int gr = row0 + rg * 4 + i;
        if (gr < N) {
            float4 o;
            o.x = acc[i][0] + bv.x; o.y = acc[i][1] + bv.y;
            o.z = acc[i][2] + bv.z; o.w = acc[i][3] + bv.w;
            *(float4*)&Y[gr * FOUT + cg * 4] = o;
        }
    }
}

// ---------------------------------------------------------------------------
// Wave-per-segment gather-sum (segment id wave-uniform -> scalar offs/lst
// loads; unroll x4 keeps 4 row gathers in flight; register accumulate).
// ---------------------------------------------------------------------------
template<bool RELU>
__global__ __launch_bounds__(256) void seg_gather_f128(
    const float* __restrict__ SRC, const int* __restrict__ offs,
    const int* __restrict__ lst, const float* __restrict__ inv,
    float* __restrict__ DST, int nseg)
{
    int s = blockIdx.x * 4 + (threadIdx.x >> 6);
    s = __builtin_amdgcn_readfirstlane(s);
    if (s >= nseg) return;
    const int lane = threadIdx.x & 63;
    int p   = offs[s];
    const int end = offs[s + 1];
    const float* srcl = SRC + lane * 2;
    float ax = 0.f, ay = 0.f;
    for (; p + 4 <= end; p += 4) {
        int r0 = lst[p], r1 = lst[p + 1], r2 = lst[p + 2], r3 = lst[p + 3];
        float2 a0 = *(const float2*)(srcl + (size_t)r0 * 128);
        float2 a1 = *(const float2*)(srcl + (size_t)r1 * 128);
        float2 a2 = *(const float2*)(srcl + (size_t)r2 * 128);
        float2 a3 = *(const float2*)(srcl + (size_t)r3 * 128);
        ax += a0.x + a1.x + a2.x + a3.x;
        ay += a0.y + a1.y + a2.y + a3.y;
    }
    for (; p < end; ++p) {
        int r = lst[p];
        float2 a = *(const float2*)(srcl + (size_t)r * 128);
        ax += a.x; ay += a.y;
    }
    float sc = inv[s];
    ax *= sc; ay *= sc;
    if (RELU) { ax = fmaxf(ax, 0.f); ay = fmaxf(ay, 0.f); }
    float2 o; o.x = ax; o.y = ay;
    *(float2*)(DST + (size_t)s * 128 + lane * 2) = o;
}

template<bool RELU>
__global__ __launch_bounds__(256) void seg_gather_f64(
    const float* __restrict__ SRC, const int* __restrict__ offs,
    const int* __restrict__ lst, const float* __restrict__ inv,
    float* __restrict__ DST, int nseg)
{
    int s = blockIdx.x * 4 + (threadIdx.x >> 6);
    s = __builtin_amdgcn_readfirstlane(s);
    if (s >= nseg) return;
    const int lane = threadIdx.x & 63;
    const int h = lane >> 5, c = lane & 31;
    const int start = offs[s], end = offs[s + 1];
    const float* srcl = SRC + c * 2;
    float ax = 0.f, ay = 0.f;
    int p = start + h;
    for (; p + 6 < end; p += 8) {
        int r0 = lst[p], r1 = lst[p + 2], r2 = lst[p + 4], r3 = lst[p + 6];
        float2 a0 = *(const float2*)(srcl + (size_t)r0 * 64);
        float2 a1 = *(const float2*)(srcl + (size_t)r1 * 64);
        float2 a2 = *(const float2*)(srcl + (size_t)r2 * 64);
        float2 a3 = *(const float2*)(srcl + (size_t)r3 * 64);
        ax += a0.x + a1.x + a2.x + a3.x;
        ay += a0.y + a1.y + a2.y + a3.y;
    }
    for (; p < end; p += 2) {
        int r = lst[p];
        float2 a = *(const float2*)(srcl + (size_t)r * 64);
        ax += a.x; ay += a.y;
    }
    ax += __shfl_xor(ax, 32);
    ay += __shfl_xor(ay, 32);
    if (lane < 32) {
        float sc = inv[s];
        ax *= sc; ay *= sc;
        if (RELU) { ax = fmaxf(ax, 0.f); ay = fmaxf(ay, 0.f); }
        float2 o; o.x = ax; o.y = ay;
        *(float2*)(DST + (size_t)s * 64 + c * 2) = o;
    }
}

template<bool RELU>
__global__ __launch_bounds__(256) void seg_gather_f32(
    const float* __restrict__ SRC, const int* __restrict__ offs,
    const int* __restrict__ lst, const float* __restrict__ inv,
    float* __restrict__ DST, int nseg)
{
    int s = blockIdx.x * 4 + (threadIdx.x >> 6);
    s = __builtin_amdgcn_readfirstlane(s);
    if (s >= nseg) return;
    const int lane = threadIdx.x & 63;
    const int h = lane >> 5, c = lane & 31;
    const int start = offs[s], end = offs[s + 1];
    const float* srcl = SRC + c;
    float ax = 0.f;
    int p = start + h;
    for (; p + 6 < end; p += 8) {
        int r0 = lst[p], r1 = lst[p + 2], r2 = lst[p + 4], r3 = lst[p + 6];
        ax += srcl[(size_t)r0 * 32] + srcl[(size_t)r1 * 32]
            + srcl[(size_t)r2 * 32] + srcl[(size_t)r3 * 32];
    }
    for (; p < end; p += 2) {
        ax += srcl[(size_t)lst[p] * 32];
    }
    ax += __shfl_xor(ax, 32);
    if (lane < 32) {
        float o = ax * inv[s];
        if (RELU) o = fmaxf(o, 0.f);
        DST[(size_t)s * 32 + c] = o;
    }
}

// ---------------------------------------------------------------------------
extern "C" void kernel_launch(void* const* d_in, const int* in_sizes, int n_in,
                              void* d_out, int out_size, void* d_ws, size_t ws_size,
                              hipStream_t stream)
{
    const float* x  = (const float*)d_in[0];
    const int* edge = (const int*)d_in[1];
    const float* w1 = (const float*)d_in[2];
    const float* b1 = (const float*)d_in[3];
    const float* w2 = (const float*)d_in[4];
    const float* b2 = (const float*)d_in[5];
    const float* w3 = (const float*)d_in[6];
    const float* b3 = (const float*)d_in[7];
    float* out = (float*)d_out;

    const int N = N_NODES, E = N_EDGES, NNZ = NNZ_TOT;
    const int* node_idx = edge;
    const int* edge_idx = edge + NNZ;

    uintptr_t base = (uintptr_t)d_ws;
    size_t off = 0;
    auto take = [&](size_t nbytes) -> void* {
        off = (off + 255) & ~(size_t)255;
        void* p = (void*)(base + off);
        off += nbytes;
        return p;
    };
    int*   offs_e  = (int*)  take((size_t)(E + 1) * 4);
    int*   offs_v  = (int*)  take((size_t)(N + 1) * 4);
    float* Binv    = (float*)take((size_t)E * 4);
    float* Dinv    = (float*)take((size_t)N * 4);
    int*   cntBE   = (int*)  take((size_t)NB_E * 4);
    int*   cntBV   = (int*)  take((size_t)NB_V * 4);
    int*   bktOffE = (int*)  take((size_t)(NB_E + 1) * 4);
    int*   bktOffV = (int*)  take((size_t)(NB_V + 1) * 4);
    int*   curBE   = (int*)  take((size_t)NB_E * 4);
    int*   curBV   = (int*)  take((size_t)NB_V * 4);
    int*   csrE    = (int*)  take((size_t)NNZ * 4);
    int*   csrV    = (int*)  take((size_t)NNZ * 4);
    float* xw      = (float*)take((size_t)N * 128 * 4);
    float* hA      = (float*)take((size_t)N * 128 * 4);
    float* hB      = (float*)take((size_t)N * 64 * 4);
    float* me      = (float*)take((size_t)E * 128 * 4);

    // bucket arrays alias hA: dead until the layer-1 node gather, long after
    // csr_finalize consumes them (single stream, sequential dependencies)
    unsigned int* bktE = (unsigned int*)hA;
    unsigned int* bktV = bktE + NNZ;

    hipMemsetAsync(cntBE, 0, (size_t)NB_E * 4, stream);
    hipMemsetAsync(cntBV, 0, (size_t)NB_V * 4, stream);

    bucket_count_kernel<<<(NNZ + 16383) / 16384, 1024, 0, stream>>>(
        node_idx, edge_idx, cntBE, cntBV, NNZ);
    bucket_scan_kernel<<<2, 1024, 0, stream>>>(
        cntBE, bktOffE, curBE, offs_e, cntBV, bktOffV, curBV, offs_v);
    bucket_write_kernel<<<(NNZ + 16383) / 16384, 1024, 0, stream>>>(
        node_idx, edge_idx, curBE, curBV, bktE, bktV, NNZ);
    csr_finalize_kernel<<<NB_E + NB_V, 256, 0, stream>>>(
        bktE, bktV, bktOffE, bktOffV, offs_e, offs_v, Binv, Dinv, csrE, csrV);

    // Layer 1: 128 -> 128
    gemm_bias<128, 128><<<(N + 31) / 32, 256, 0, stream>>>(x, w1, b1, xw, N);
    seg_gather_f128<false><<<(E + 3) / 4, 256, 0, stream>>>(xw, offs_e, csrE, Binv, me, E);
    seg_gather_f128<true ><<<(N + 3) / 4, 256, 0, stream>>>(me, offs_v, csrV, Dinv, hA, N);

    // Layer 2: 128 -> 64
    gemm_bias<128, 64><<<(N + 63) / 64, 256, 0, stream>>>(hA, w2, b2, xw, N);
    seg_gather_f64<false><<<(E + 3) / 4, 256, 0, stream>>>(xw, offs_e, csrE, Binv, me, E);
    seg_gather_f64<true ><<<(N + 3) / 4, 256, 0, stream>>>(me, offs_v, csrV, Dinv, hB, N);

    // Layer 3: 64 -> 32
    gemm_bias<64, 32><<<(N + 127) / 128, 256, 0, stream>>>(hB, w3, b3, xw, N);
    seg_gather_f32<false><<<(E + 3) / 4, 256, 0, stream>>>(xw, offs_e, csrE, Binv, me, E);
    seg_gather_f32<true ><<<(N + 3) / 4, 256, 0, stream>>>(me, offs_v, csrV, Dinv, out, N);
}

// Round 5
// 338.967 us; speedup vs baseline: 2.2662x; 1.0770x over previous
//
#include <hip/hip_runtime.h>

#define N_NODES   50000
#define N_EDGES   10000
#define NNZ_TOT   800000

// Bucketing geometry for the two-phase CSR build
#define SW_E 16                      // edges per E-bucket
#define NB_E 625                     // 10000/16
#define SW_V 64                      // nodes per V-bucket
#define NB_V 782                     // ceil(50000/64)

// ---------------------------------------------------------------------------
// Step 1: coarse bucket counts. LDS histograms, one global atomic per
// (block,bucket): ~69k atomics on a 5.6KB table (vs 1.6M fine atomics).
// ---------------------------------------------------------------------------
__global__ __launch_bounds__(1024) void bucket_count_kernel(
    const int* __restrict__ node_idx, const int* __restrict__ edge_idx,
    int* __restrict__ cntBE, int* __restrict__ cntBV, int nnz)
{
    __shared__ int hE[NB_E];
    __shared__ int hV[NB_V];
    const int tid = threadIdx.x;
    for (int t = tid; t < NB_E; t += 1024) hE[t] = 0;
    for (int t = tid; t < NB_V; t += 1024) hV[t] = 0;
    __syncthreads();

    const int base = blockIdx.x * 16384;
    #pragma unroll
    for (int j = 0; j < 16; ++j) {
        int k = base + j * 1024 + tid;
        if (k < nnz) {
            unsigned int v = (unsigned int)node_idx[k];
            unsigned int e = (unsigned int)edge_idx[k];
            atomicAdd(&hE[e >> 4], 1);
            atomicAdd(&hV[v >> 6], 1);
        }
    }
    __syncthreads();
    for (int t = tid; t < NB_E; t += 1024) { int c = hE[t]; if (c) atomicAdd(&cntBE[t], c); }
    for (int t = tid; t < NB_V; t += 1024) { int c = hV[t]; if (c) atomicAdd(&cntBV[t], c); }
}

// ---------------------------------------------------------------------------
// Step 2: exclusive scan of bucket counts -> bucket bases + scatter cursors.
// ---------------------------------------------------------------------------
__global__ __launch_bounds__(1024) void bucket_scan_kernel(
    const int* __restrict__ cntBE, int* __restrict__ bktOffE, int* __restrict__ curBE,
    int* __restrict__ offs_e,
    const int* __restrict__ cntBV, int* __restrict__ bktOffV, int* __restrict__ curBV,
    int* __restrict__ offs_v)
{
    const int* cnt; int* bktOff; int* curB; int nb;
    if (blockIdx.x == 0) {
        cnt = cntBE; bktOff = bktOffE; curB = curBE; nb = NB_E;
        if (threadIdx.x == 0) offs_e[N_EDGES] = NNZ_TOT;
    } else {
        cnt = cntBV; bktOff = bktOffV; curB = curBV; nb = NB_V;
        if (threadIdx.x == 0) offs_v[N_NODES] = NNZ_TOT;
    }

    __shared__ int wtot[16];
    const int tid  = threadIdx.x;
    const int lane = tid & 63;
    const int w    = tid >> 6;

    int val = (tid < nb) ? cnt[tid] : 0;
    int x = val;
    #pragma unroll
    for (int d = 1; d < 64; d <<= 1) {
        int y = __shfl_up(x, d, 64);
        if (lane >= d) x += y;
    }
    if (lane == 63) wtot[w] = x;
    __syncthreads();
    if (w == 0) {
        int t = (lane < 16) ? wtot[lane] : 0;
        #pragma unroll
        for (int d = 1; d < 16; d <<= 1) {
            int y = __shfl_up(t, d, 64);
            if (lane >= d) t += y;
        }
        if (lane < 16) wtot[lane] = t;
    }
    __syncthreads();
    int incl = x + ((w > 0) ? wtot[w - 1] : 0);
    int excl = incl - val;
    if (tid < nb) {
        bktOff[tid] = excl;
        curB[tid]   = excl;
    }
    if (tid == 0) bktOff[nb] = NNZ_TOT;
}

// ---------------------------------------------------------------------------
// Step 3: bucket-sort incidences, both directions (contiguous per-block runs
// inside bucket slices: single-owner lines, no writeback blowup).
// ---------------------------------------------------------------------------
__global__ __launch_bounds__(1024) void bucket_write_kernel(
    const int* __restrict__ node_idx, const int* __restrict__ edge_idx,
    int* __restrict__ curBE, int* __restrict__ curBV,
    unsigned int* __restrict__ bktE, unsigned int* __restrict__ bktV, int nnz)
{
    __shared__ int hE[NB_E];
    __shared__ int hV[NB_V];
    const int tid = threadIdx.x;
    for (int t = tid; t < NB_E; t += 1024) hE[t] = 0;
    for (int t = tid; t < NB_V; t += 1024) hV[t] = 0;
    __syncthreads();

    unsigned int pE[16], pV[16];
    const int base = blockIdx.x * 16384;
    #pragma unroll
    for (int j = 0; j < 16; ++j) {
        int k = base + j * 1024 + tid;
        if (k < nnz) {
            unsigned int v = (unsigned int)node_idx[k];
            unsigned int e = (unsigned int)edge_idx[k];
            pE[j] = (e << 16) | v;
            pV[j] = (v << 16) | e;
            atomicAdd(&hE[e >> 4], 1);
            atomicAdd(&hV[v >> 6], 1);
        } else { pE[j] = 0xFFFFFFFFu; pV[j] = 0xFFFFFFFFu; }
    }
    __syncthreads();
    for (int t = tid; t < NB_E; t += 1024) {
        int c = hE[t];
        hE[t] = c ? atomicAdd(&curBE[t], c) : 0;
    }
    for (int t = tid; t < NB_V; t += 1024) {
        int c = hV[t];
        hV[t] = c ? atomicAdd(&curBV[t], c) : 0;
    }
    __syncthreads();
    #pragma unroll
    for (int j = 0; j < 16; ++j) {
        if (pE[j] != 0xFFFFFFFFu) {
            int se = atomicAdd(&hE[pE[j] >> 20], 1);   // pack>>20 == e>>4
            bktE[se] = pE[j];
            int sv = atomicAdd(&hV[pV[j] >> 22], 1);   // pack>>22 == v>>6
            bktV[sv] = pV[j];
        }
    }
}

// ---------------------------------------------------------------------------
// Step 4: per bucket: fine counts -> wave-scan -> offs/inv/cursors -> rank &
// write CSR payload. Zero global atomics; slice is L2-hot.
// ---------------------------------------------------------------------------
__global__ __launch_bounds__(256) void csr_finalize_kernel(
    const unsigned int* __restrict__ bktE, const unsigned int* __restrict__ bktV,
    const int* __restrict__ bktOffE, const int* __restrict__ bktOffV,
    int* __restrict__ offs_e, int* __restrict__ offs_v,
    float* __restrict__ Binv, float* __restrict__ Dinv,
    int* __restrict__ csrE, int* __restrict__ csrV)
{
    __shared__ int cnt[SW_V];
    __shared__ int cur[SW_V];
    int b = blockIdx.x;
    const unsigned int* bkt; const int* bktOff; int* offs; float* inv; int* csr;
    int lo, sw, nseg;
    if (b < NB_E) {
        bkt = bktE; bktOff = bktOffE; offs = offs_e; inv = Binv; csr = csrE;
        sw = SW_E; lo = b * SW_E; nseg = N_EDGES;
    } else {
        b -= NB_E;
        bkt = bktV; bktOff = bktOffV; offs = offs_v; inv = Dinv; csr = csrV;
        sw = SW_V; lo = b * SW_V; nseg = N_NODES;
    }
    int hi = lo + sw; if (hi > nseg) hi = nseg;
    const int ns = hi - lo;
    const int p0 = bktOff[b], p1 = bktOff[b + 1];

    if (threadIdx.x < ns) cnt[threadIdx.x] = 0;
    __syncthreads();
    for (int p = p0 + threadIdx.x; p < p1; p += 256) {
        int key = (int)(bkt[p] >> 16);
        atomicAdd(&cnt[key - lo], 1);
    }
    __syncthreads();
    if (threadIdx.x < 64) {
        int lane = threadIdx.x;
        int val = (lane < ns) ? cnt[lane] : 0;
        int x = val;
        #pragma unroll
        for (int d = 1; d < 64; d <<= 1) {
            int y = __shfl_up(x, d, 64);
            if (lane >= d) x += y;
        }
        int excl = x - val;
        if (lane < ns) {
            offs[lo + lane] = p0 + excl;
            inv[lo + lane]  = (val > 0) ? (1.0f / (float)val) : 0.0f;
            cur[lane]       = p0 + excl;
        }
    }
    __syncthreads();
    for (int p = p0 + threadIdx.x; p < p1; p += 256) {
        unsigned int pk = bkt[p];
        int key  = (int)(pk >> 16);
        int slot = atomicAdd(&cur[key - lo], 1);
        csr[slot] = (int)(pk & 0xFFFFu);
    }
}

// ---------------------------------------------------------------------------
// fp32 GEMM  Y[N,FOUT] = X[N,FIN] @ W[FIN,FOUT] + bias   (vector FMA; no fp32
// MFMA on CDNA4). Block 256 thr, tile BM x FOUT, thread tile 8 x (4*NH).
// Xs is k-major so the 8-row X fragment is 2x ds_read_b128 (wave-broadcast,
// conflict-free). W cols come as NH float4s from split halves (banks 4*cg:
// 2-way aliasing only = free). 64 (resp 32) independent FMA per k per thread
// hides LDS latency in-wave even at low occupancy.
// ---------------------------------------------------------------------------
template<int FIN, int FOUT, int BM, int NH>
__global__ __launch_bounds__(256) void gemm_bias(
    const float* __restrict__ X, const float* __restrict__ W,
    const float* __restrict__ Bias, float* __restrict__ Y, int N)
{
    constexpr int KB  = 32;
    constexpr int CGN = FOUT / (4 * NH);     // col groups
    constexpr int RGN = 256 / CGN;           // row groups
    constexpr int TM  = BM / RGN;            // rows per thread
    static_assert(TM == 8, "thread tile is 8 rows");
    constexpr int HO  = FOUT / 2;            // half offset (NH==2)

    __shared__ float Xs[KB][BM + 4];         // +4: keeps rows 16B-aligned
    __shared__ float Ws[KB][FOUT];

    const int tid  = threadIdx.x;
    const int cg   = tid % CGN;
    const int rg   = tid / CGN;
    const int row0 = blockIdx.x * BM;

    float acc[8][4 * NH];
    #pragma unroll
    for (int i = 0; i < 8; ++i)
        #pragma unroll
        for (int j = 0; j < 4 * NH; ++j) acc[i][j] = 0.f;

    for (int k0 = 0; k0 < FIN; k0 += KB) {
        // stage X transposed: Xs[k][r]
        constexpr int XIT = BM / 32;         // (BM*KB/4) / 256
        #pragma unroll
        for (int it = 0; it < XIT; ++it) {
            int idx = tid + it * 256;
            int r   = idx >> 3;
            int kq  = idx & 7;
            int gr  = row0 + r; if (gr >= N) gr = N - 1;   // clamp; result unused
            float4 v = *(const float4*)&X[(size_t)gr * FIN + k0 + kq * 4];
            Xs[kq * 4 + 0][r] = v.x;
            Xs[kq * 4 + 1][r] = v.y;
            Xs[kq * 4 + 2][r] = v.z;
            Xs[kq * 4 + 3][r] = v.w;
        }
        // stage W natural layout
        constexpr int WIT = FOUT / 32;       // (KB*FOUT/4) / 256
        #pragma unroll
        for (int it = 0; it < WIT; ++it) {
            int idx = tid + it * 256;
            int k   = idx / (FOUT / 4);
            int cq  = idx % (FOUT / 4);
            *(float4*)&Ws[k][cq * 4] = *(const float4*)&W[(size_t)(k0 + k) * FOUT + cq * 4];
        }
        __syncthreads();

        #pragma unroll 4
        for (int k = 0; k < KB; ++k) {
            float4 xa = *(const float4*)&Xs[k][rg * 8];
            float4 xb = *(const float4*)&Xs[k][rg * 8 + 4];
            float4 w0 = *(const float4*)&Ws[k][cg * 4];
            float4 w1;
            if (NH == 2) w1 = *(const float4*)&Ws[k][HO + cg * 4];
            float xr[8] = { xa.x, xa.y, xa.z, xa.w, xb.x, xb.y, xb.z, xb.w };
            #pragma unroll
            for (int i = 0; i < 8; ++i) {
                acc[i][0] += xr[i] * w0.x;
                acc[i][1] += xr[i] * w0.y;
                acc[i][2] += xr[i] * w0.z;
                acc[i][3] += xr[i] * w0.w;
                if (NH == 2) {
                    acc[i][4] += xr[i] * w1.x;
                    acc[i][5] += xr[i] * w1.y;
                    acc[i][6] += xr[i] * w1.z;
                    acc[i][7] += xr[i] * w1.w;
                }
            }
        }
        __syncthreads();
    }

    float4 b0 = *(const float4*)&Bias[cg * 4];
    float4 b1;
    if (NH == 2) b1 = *(const float4*)&Bias[HO + cg * 4];
    #pragma unroll
    for (int i = 0; i < 8; ++i) {
        int gr = row0 + rg * 8 + i;
        if (gr < N) {
            float4 o0;
            o0.x = acc[i][0] + b0.x; o0.y = acc[i][1] + b0.y;
            o0.z = acc[i][2] + b0.z; o0.w = acc[i][3] + b0.w;
            *(float4*)&Y[(size_t)gr * FOUT + cg * 4] = o0;
            if (NH == 2) {
                float4 o1;
                o1.x = acc[i][4] + b1.x; o1.y = acc[i][5] + b1.y;
                o1.z = acc[i][6] + b1.z; o1.w = acc[i][7] + b1.w;
                *(float4*)&Y[(size_t)gr * FOUT + HO + cg * 4] = o1;
            }
        }
    }
}

// ---------------------------------------------------------------------------
// Wave-per-segment gather-sum (segment id wave-uniform -> scalar offs/lst
// loads; unroll x4 keeps 4 row gathers in flight; register accumulate).
// ---------------------------------------------------------------------------
template<bool RELU>
__global__ __launch_bounds__(256) void seg_gather_f128(
    const float* __restrict__ SRC, const int* __restrict__ offs,
    const int* __restrict__ lst, const float* __restrict__ inv,
    float* __restrict__ DST, int nseg)
{
    int s = blockIdx.x * 4 + (threadIdx.x >> 6);
    s = __builtin_amdgcn_readfirstlane(s);
    if (s >= nseg) return;
    const int lane = threadIdx.x & 63;
    int p   = offs[s];
    const int end = offs[s + 1];
    const float* srcl = SRC + lane * 2;
    float ax = 0.f, ay = 0.f;
    for (; p + 4 <= end; p += 4) {
        int r0 = lst[p], r1 = lst[p + 1], r2 = lst[p + 2], r3 = lst[p + 3];
        float2 a0 = *(const float2*)(srcl + (size_t)r0 * 128);
        float2 a1 = *(const float2*)(srcl + (size_t)r1 * 128);
        float2 a2 = *(const float2*)(srcl + (size_t)r2 * 128);
        float2 a3 = *(const float2*)(srcl + (size_t)r3 * 128);
        ax += a0.x + a1.x + a2.x + a3.x;
        ay += a0.y + a1.y + a2.y + a3.y;
    }
    for (; p < end; ++p) {
        int r = lst[p];
        float2 a = *(const float2*)(srcl + (size_t)r * 128);
        ax += a.x; ay += a.y;
    }
    float sc = inv[s];
    ax *= sc; ay *= sc;
    if (RELU) { ax = fmaxf(ax, 0.f); ay = fmaxf(ay, 0.f); }
    float2 o; o.x = ax; o.y = ay;
    *(float2*)(DST + (size_t)s * 128 + lane * 2) = o;
}

template<bool RELU>
__global__ __launch_bounds__(256) void seg_gather_f64(
    const float* __restrict__ SRC, const int* __restrict__ offs,
    const int* __restrict__ lst, const float* __restrict__ inv,
    float* __restrict__ DST, int nseg)
{
    int s = blockIdx.x * 4 + (threadIdx.x >> 6);
    s = __builtin_amdgcn_readfirstlane(s);
    if (s >= nseg) return;
    const int lane = threadIdx.x & 63;
    const int h = lane >> 5, c = lane & 31;
    const int start = offs[s], end = offs[s + 1];
    const float* srcl = SRC + c * 2;
    float ax = 0.f, ay = 0.f;
    int p = start + h;
    for (; p + 6 < end; p += 8) {
        int r0 = lst[p], r1 = lst[p + 2], r2 = lst[p + 4], r3 = lst[p + 6];
        float2 a0 = *(const float2*)(srcl + (size_t)r0 * 64);
        float2 a1 = *(const float2*)(srcl + (size_t)r1 * 64);
        float2 a2 = *(const float2*)(srcl + (size_t)r2 * 64);
        float2 a3 = *(const float2*)(srcl + (size_t)r3 * 64);
        ax += a0.x + a1.x + a2.x + a3.x;
        ay += a0.y + a1.y + a2.y + a3.y;
    }
    for (; p < end; p += 2) {
        int r = lst[p];
        float2 a = *(const float2*)(srcl + (size_t)r * 64);
        ax += a.x; ay += a.y;
    }
    ax += __shfl_xor(ax, 32);
    ay += __shfl_xor(ay, 32);
    if (lane < 32) {
        float sc = inv[s];
        ax *= sc; ay *= sc;
        if (RELU) { ax = fmaxf(ax, 0.f); ay = fmaxf(ay, 0.f); }
        float2 o; o.x = ax; o.y = ay;
        *(float2*)(DST + (size_t)s * 64 + c * 2) = o;
    }
}

template<bool RELU>
__global__ __launch_bounds__(256) void seg_gather_f32(
    const float* __restrict__ SRC, const int* __restrict__ offs,
    const int* __restrict__ lst, const float* __restrict__ inv,
    float* __restrict__ DST, int nseg)
{
    int s = blockIdx.x * 4 + (threadIdx.x >> 6);
    s = __builtin_amdgcn_readfirstlane(s);
    if (s >= nseg) return;
    const int lane = threadIdx.x & 63;
    const int h = lane >> 5, c = lane & 31;
    const int start = offs[s], end = offs[s + 1];
    const float* srcl = SRC + c;
    float ax = 0.f;
    int p = start + h;
    for (; p + 6 < end; p += 8) {
        int r0 = lst[p], r1 = lst[p + 2], r2 = lst[p + 4], r3 = lst[p + 6];
        ax += srcl[(size_t)r0 * 32] + srcl[(size_t)r1 * 32]
            + srcl[(size_t)r2 * 32] + srcl[(size_t)r3 * 32];
    }
    for (; p < end; p += 2) {
        ax += srcl[(size_t)lst[p] * 32];
    }
    ax += __shfl_xor(ax, 32);
    if (lane < 32) {
        float o = ax * inv[s];
        if (RELU) o = fmaxf(o, 0.f);
        DST[(size_t)s * 32 + c] = o;
    }
}

// ---------------------------------------------------------------------------
extern "C" void kernel_launch(void* const* d_in, const int* in_sizes, int n_in,
                              void* d_out, int out_size, void* d_ws, size_t ws_size,
                              hipStream_t stream)
{
    const float* x  = (const float*)d_in[0];
    const int* edge = (const int*)d_in[1];
    const float* w1 = (const float*)d_in[2];
    const float* b1 = (const float*)d_in[3];
    const float* w2 = (const float*)d_in[4];
    const float* b2 = (const float*)d_in[5];
    const float* w3 = (const float*)d_in[6];
    const float* b3 = (const float*)d_in[7];
    float* out = (float*)d_out;

    const int N = N_NODES, E = N_EDGES, NNZ = NNZ_TOT;
    const int* node_idx = edge;
    const int* edge_idx = edge + NNZ;

    uintptr_t base = (uintptr_t)d_ws;
    size_t off = 0;
    auto take = [&](size_t nbytes) -> void* {
        off = (off + 255) & ~(size_t)255;
        void* p = (void*)(base + off);
        off += nbytes;
        return p;
    };
    int*   offs_e  = (int*)  take((size_t)(E + 1) * 4);
    int*   offs_v  = (int*)  take((size_t)(N + 1) * 4);
    float* Binv    = (float*)take((size_t)E * 4);
    float* Dinv    = (float*)take((size_t)N * 4);
    int*   cntBE   = (int*)  take((size_t)NB_E * 4);
    int*   cntBV   = (int*)  take((size_t)NB_V * 4);
    int*   bktOffE = (int*)  take((size_t)(NB_E + 1) * 4);
    int*   bktOffV = (int*)  take((size_t)(NB_V + 1) * 4);
    int*   curBE   = (int*)  take((size_t)NB_E * 4);
    int*   curBV   = (int*)  take((size_t)NB_V * 4);
    int*   csrE    = (int*)  take((size_t)NNZ * 4);
    int*   csrV    = (int*)  take((size_t)NNZ * 4);
    float* xw      = (float*)take((size_t)N * 128 * 4);
    float* hA      = (float*)take((size_t)N * 128 * 4);
    float* hB      = (float*)take((size_t)N * 64 * 4);
    float* me      = (float*)take((size_t)E * 128 * 4);

    // bucket arrays alias hA: dead until the layer-1 node gather, long after
    // csr_finalize consumes them (single stream, sequential dependencies)
    unsigned int* bktE = (unsigned int*)hA;
    unsigned int* bktV = bktE + NNZ;

    hipMemsetAsync(cntBE, 0, (size_t)NB_E * 4, stream);
    hipMemsetAsync(cntBV, 0, (size_t)NB_V * 4, stream);

    bucket_count_kernel<<<(NNZ + 16383) / 16384, 1024, 0, stream>>>(
        node_idx, edge_idx, cntBE, cntBV, NNZ);
    bucket_scan_kernel<<<2, 1024, 0, stream>>>(
        cntBE, bktOffE, curBE, offs_e, cntBV, bktOffV, curBV, offs_v);
    bucket_write_kernel<<<(NNZ + 16383) / 16384, 1024, 0, stream>>>(
        node_idx, edge_idx, curBE, curBV, bktE, bktV, NNZ);
    csr_finalize_kernel<<<NB_E + NB_V, 256, 0, stream>>>(
        bktE, bktV, bktOffE, bktOffV, offs_e, offs_v, Binv, Dinv, csrE, csrV);

    // Layer 1: 128 -> 128   (BM=128, thread tile 8x8)
    gemm_bias<128, 128, 128, 2><<<(N + 127) / 128, 256, 0, stream>>>(x, w1, b1, xw, N);
    seg_gather_f128<false><<<(E + 3) / 4, 256, 0, stream>>>(xw, offs_e, csrE, Binv, me, E);
    seg_gather_f128<true ><<<(N + 3) / 4, 256, 0, stream>>>(me, offs_v, csrV, Dinv, hA, N);

    // Layer 2: 128 -> 64    (BM=128, thread tile 8x4)
    gemm_bias<128, 64, 128, 1><<<(N + 127) / 128, 256, 0, stream>>>(hA, w2, b2, xw, N);
    seg_gather_f64<false><<<(E + 3) / 4, 256, 0, stream>>>(xw, offs_e, csrE, Binv, me, E);
    seg_gather_f64<true ><<<(N + 3) / 4, 256, 0, stream>>>(me, offs_v, csrV, Dinv, hB, N);

    // Layer 3: 64 -> 32     (BM=256, thread tile 8x4)
    gemm_bias<64, 32, 256, 1><<<(N + 255) / 256, 256, 0, stream>>>(hB, w3, b3, xw, N);
    seg_gather_f32<false><<<(E + 3) / 4, 256, 0, stream>>>(xw, offs_e, csrE, Binv, me, E);
    seg_gather_f32<true ><<<(N + 3) / 4, 256, 0, stream>>>(me, offs_v, csrV, Dinv, out, N);
}

// Round 6
// 300.336 us; speedup vs baseline: 2.5576x; 1.1286x over previous
//
#include <hip/hip_runtime.h>

#define N_NODES   50000
#define N_EDGES   10000
#define NNZ_TOT   800000

// Bucketing geometry for the two-phase CSR build
#define SW_E 16                      // edges per E-bucket
#define NB_E 625                     // 10000/16
#define SW_V 64                      // nodes per V-bucket
#define NB_V 782                     // ceil(50000/64)

// ---------------------------------------------------------------------------
// Step 1: coarse bucket counts. LDS histograms, one global atomic per
// (block,bucket): ~69k atomics on a 5.6KB table (vs 1.6M fine atomics).
// ---------------------------------------------------------------------------
__global__ __launch_bounds__(1024) void bucket_count_kernel(
    const int* __restrict__ node_idx, const int* __restrict__ edge_idx,
    int* __restrict__ cntBE, int* __restrict__ cntBV, int nnz)
{
    __shared__ int hE[NB_E];
    __shared__ int hV[NB_V];
    const int tid = threadIdx.x;
    for (int t = tid; t < NB_E; t += 1024) hE[t] = 0;
    for (int t = tid; t < NB_V; t += 1024) hV[t] = 0;
    __syncthreads();

    const int base = blockIdx.x * 16384;
    #pragma unroll
    for (int j = 0; j < 16; ++j) {
        int k = base + j * 1024 + tid;
        if (k < nnz) {
            unsigned int v = (unsigned int)node_idx[k];
            unsigned int e = (unsigned int)edge_idx[k];
            atomicAdd(&hE[e >> 4], 1);
            atomicAdd(&hV[v >> 6], 1);
        }
    }
    __syncthreads();
    for (int t = tid; t < NB_E; t += 1024) { int c = hE[t]; if (c) atomicAdd(&cntBE[t], c); }
    for (int t = tid; t < NB_V; t += 1024) { int c = hV[t]; if (c) atomicAdd(&cntBV[t], c); }
}

// ---------------------------------------------------------------------------
// Step 2: exclusive scan of bucket counts -> bucket bases + scatter cursors.
// ---------------------------------------------------------------------------
__global__ __launch_bounds__(1024) void bucket_scan_kernel(
    const int* __restrict__ cntBE, int* __restrict__ bktOffE, int* __restrict__ curBE,
    int* __restrict__ offs_e,
    const int* __restrict__ cntBV, int* __restrict__ bktOffV, int* __restrict__ curBV,
    int* __restrict__ offs_v)
{
    const int* cnt; int* bktOff; int* curB; int nb;
    if (blockIdx.x == 0) {
        cnt = cntBE; bktOff = bktOffE; curB = curBE; nb = NB_E;
        if (threadIdx.x == 0) offs_e[N_EDGES] = NNZ_TOT;
    } else {
        cnt = cntBV; bktOff = bktOffV; curB = curBV; nb = NB_V;
        if (threadIdx.x == 0) offs_v[N_NODES] = NNZ_TOT;
    }

    __shared__ int wtot[16];
    const int tid  = threadIdx.x;
    const int lane = tid & 63;
    const int w    = tid >> 6;

    int val = (tid < nb) ? cnt[tid] : 0;
    int x = val;
    #pragma unroll
    for (int d = 1; d < 64; d <<= 1) {
        int y = __shfl_up(x, d, 64);
        if (lane >= d) x += y;
    }
    if (lane == 63) wtot[w] = x;
    __syncthreads();
    if (w == 0) {
        int t = (lane < 16) ? wtot[lane] : 0;
        #pragma unroll
        for (int d = 1; d < 16; d <<= 1) {
            int y = __shfl_up(t, d, 64);
            if (lane >= d) t += y;
        }
        if (lane < 16) wtot[lane] = t;
    }
    __syncthreads();
    int incl = x + ((w > 0) ? wtot[w - 1] : 0);
    int excl = incl - val;
    if (tid < nb) {
        bktOff[tid] = excl;
        curB[tid]   = excl;
    }
    if (tid == 0) bktOff[nb] = NNZ_TOT;
}

// ---------------------------------------------------------------------------
// Step 3: bucket-sort incidences, both directions (contiguous per-block runs
// inside bucket slices: single-owner lines, no writeback blowup).
// ---------------------------------------------------------------------------
__global__ __launch_bounds__(1024) void bucket_write_kernel(
    const int* __restrict__ node_idx, const int* __restrict__ edge_idx,
    int* __restrict__ curBE, int* __restrict__ curBV,
    unsigned int* __restrict__ bktE, unsigned int* __restrict__ bktV, int nnz)
{
    __shared__ int hE[NB_E];
    __shared__ int hV[NB_V];
    const int tid = threadIdx.x;
    for (int t = tid; t < NB_E; t += 1024) hE[t] = 0;
    for (int t = tid; t < NB_V; t += 1024) hV[t] = 0;
    __syncthreads();

    unsigned int pE[16], pV[16];
    const int base = blockIdx.x * 16384;
    #pragma unroll
    for (int j = 0; j < 16; ++j) {
        int k = base + j * 1024 + tid;
        if (k < nnz) {
            unsigned int v = (unsigned int)node_idx[k];
            unsigned int e = (unsigned int)edge_idx[k];
            pE[j] = (e << 16) | v;
            pV[j] = (v << 16) | e;
            atomicAdd(&hE[e >> 4], 1);
            atomicAdd(&hV[v >> 6], 1);
        } else { pE[j] = 0xFFFFFFFFu; pV[j] = 0xFFFFFFFFu; }
    }
    __syncthreads();
    for (int t = tid; t < NB_E; t += 1024) {
        int c = hE[t];
        hE[t] = c ? atomicAdd(&curBE[t], c) : 0;
    }
    for (int t = tid; t < NB_V; t += 1024) {
        int c = hV[t];
        hV[t] = c ? atomicAdd(&curBV[t], c) : 0;
    }
    __syncthreads();
    #pragma unroll
    for (int j = 0; j < 16; ++j) {
        if (pE[j] != 0xFFFFFFFFu) {
            int se = atomicAdd(&hE[pE[j] >> 20], 1);   // pack>>20 == e>>4
            bktE[se] = pE[j];
            int sv = atomicAdd(&hV[pV[j] >> 22], 1);   // pack>>22 == v>>6
            bktV[sv] = pV[j];
        }
    }
}

// ---------------------------------------------------------------------------
// Step 4: per bucket: fine counts -> wave-scan -> offs/inv/cursors -> rank &
// write CSR payload. Zero global atomics; slice is L2-hot.
// ---------------------------------------------------------------------------
__global__ __launch_bounds__(256) void csr_finalize_kernel(
    const unsigned int* __restrict__ bktE, const unsigned int* __restrict__ bktV,
    const int* __restrict__ bktOffE, const int* __restrict__ bktOffV,
    int* __restrict__ offs_e, int* __restrict__ offs_v,
    float* __restrict__ Binv, float* __restrict__ Dinv,
    int* __restrict__ csrE, int* __restrict__ csrV)
{
    __shared__ int cnt[SW_V];
    __shared__ int cur[SW_V];
    int b = blockIdx.x;
    const unsigned int* bkt; const int* bktOff; int* offs; float* inv; int* csr;
    int lo, sw, nseg;
    if (b < NB_E) {
        bkt = bktE; bktOff = bktOffE; offs = offs_e; inv = Binv; csr = csrE;
        sw = SW_E; lo = b * SW_E; nseg = N_EDGES;
    } else {
        b -= NB_E;
        bkt = bktV; bktOff = bktOffV; offs = offs_v; inv = Dinv; csr = csrV;
        sw = SW_V; lo = b * SW_V; nseg = N_NODES;
    }
    int hi = lo + sw; if (hi > nseg) hi = nseg;
    const int ns = hi - lo;
    const int p0 = bktOff[b], p1 = bktOff[b + 1];

    if (threadIdx.x < ns) cnt[threadIdx.x] = 0;
    __syncthreads();
    for (int p = p0 + threadIdx.x; p < p1; p += 256) {
        int key = (int)(bkt[p] >> 16);
        atomicAdd(&cnt[key - lo], 1);
    }
    __syncthreads();
    if (threadIdx.x < 64) {
        int lane = threadIdx.x;
        int val = (lane < ns) ? cnt[lane] : 0;
        int x = val;
        #pragma unroll
        for (int d = 1; d < 64; d <<= 1) {
            int y = __shfl_up(x, d, 64);
            if (lane >= d) x += y;
        }
        int excl = x - val;
        if (lane < ns) {
            offs[lo + lane] = p0 + excl;
            inv[lo + lane]  = (val > 0) ? (1.0f / (float)val) : 0.0f;
            cur[lane]       = p0 + excl;
        }
    }
    __syncthreads();
    for (int p = p0 + threadIdx.x; p < p1; p += 256) {
        unsigned int pk = bkt[p];
        int key  = (int)(pk >> 16);
        int slot = atomicAdd(&cur[key - lo], 1);
        csr[slot] = (int)(pk & 0xFFFFu);
    }
}

// ---------------------------------------------------------------------------
// fp32 GEMM  Y[N,FOUT] = X[N,FIN] @ W[FIN,FOUT] + bias   (vector FMA; no fp32
// MFMA on CDNA4). 256 thr, tile BM x FOUT, thread tile 4 x (4*NH).
// BM=64 -> 782 blocks (~3/CU, ~12 waves/CU): occupancy was the R4 limiter
// (391 blocks -> 13.6%). Per k: 1 X ds_read_b128 (16-lane broadcast) +
// NH W ds_read_b128 (16 distinct 16B addrs = 2-way bank aliasing = free).
// ---------------------------------------------------------------------------
template<int FIN, int FOUT, int BM, int NH>
__global__ __launch_bounds__(256) void gemm_bias(
    const float* __restrict__ X, const float* __restrict__ W,
    const float* __restrict__ Bias, float* __restrict__ Y, int N)
{
    constexpr int KB  = 32;
    constexpr int CGN = FOUT / (4 * NH);     // col groups
    constexpr int RGN = 256 / CGN;           // row groups
    static_assert(RGN * 4 == BM, "thread tile is 4 rows");
    constexpr int HO  = FOUT / 2;            // half offset (NH==2)

    __shared__ float Xs[KB][BM + 4];         // k-major; +4 keeps 16B alignment
    __shared__ float Ws[KB][FOUT];

    const int tid  = threadIdx.x;
    const int cg   = tid % CGN;
    const int rg   = tid / CGN;
    const int row0 = blockIdx.x * BM;

    float acc[4][4 * NH];
    #pragma unroll
    for (int i = 0; i < 4; ++i)
        #pragma unroll
        for (int j = 0; j < 4 * NH; ++j) acc[i][j] = 0.f;

    for (int k0 = 0; k0 < FIN; k0 += KB) {
        // stage X transposed: Xs[k][r]
        constexpr int XIT = BM / 32;         // (BM*KB/4) / 256
        #pragma unroll
        for (int it = 0; it < XIT; ++it) {
            int idx = tid + it * 256;
            int r   = idx >> 3;
            int kq  = idx & 7;
            int gr  = row0 + r; if (gr >= N) gr = N - 1;   // clamp; result unused
            float4 v = *(const float4*)&X[(size_t)gr * FIN + k0 + kq * 4];
            Xs[kq * 4 + 0][r] = v.x;
            Xs[kq * 4 + 1][r] = v.y;
            Xs[kq * 4 + 2][r] = v.z;
            Xs[kq * 4 + 3][r] = v.w;
        }
        // stage W natural layout
        constexpr int WIT = FOUT / 32;       // (KB*FOUT/4) / 256
        #pragma unroll
        for (int it = 0; it < WIT; ++it) {
            int idx = tid + it * 256;
            int k   = idx / (FOUT / 4);
            int cq  = idx % (FOUT / 4);
            *(float4*)&Ws[k][cq * 4] = *(const float4*)&W[(size_t)(k0 + k) * FOUT + cq * 4];
        }
        __syncthreads();

        #pragma unroll 8
        for (int k = 0; k < KB; ++k) {
            float4 xa = *(const float4*)&Xs[k][rg * 4];
            float4 w0 = *(const float4*)&Ws[k][cg * 4];
            float4 w1;
            if (NH == 2) w1 = *(const float4*)&Ws[k][HO + cg * 4];
            float xr[4] = { xa.x, xa.y, xa.z, xa.w };
            #pragma unroll
            for (int i = 0; i < 4; ++i) {
                acc[i][0] += xr[i] * w0.x;
                acc[i][1] += xr[i] * w0.y;
                acc[i][2] += xr[i] * w0.z;
                acc[i][3] += xr[i] * w0.w;
                if (NH == 2) {
                    acc[i][4] += xr[i] * w1.x;
                    acc[i][5] += xr[i] * w1.y;
                    acc[i][6] += xr[i] * w1.z;
                    acc[i][7] += xr[i] * w1.w;
                }
            }
        }
        __syncthreads();
    }

    float4 b0 = *(const float4*)&Bias[cg * 4];
    float4 b1;
    if (NH == 2) b1 = *(const float4*)&Bias[HO + cg * 4];
    #pragma unroll
    for (int i = 0; i < 4; ++i) {
        int gr = row0 + rg * 4 + i;
        if (gr < N) {
            float4 o0;
            o0.x = acc[i][0] + b0.x; o0.y = acc[i][1] + b0.y;
            o0.z = acc[i][2] + b0.z; o0.w = acc[i][3] + b0.w;
            *(float4*)&Y[(size_t)gr * FOUT + cg * 4] = o0;
            if (NH == 2) {
                float4 o1;
                o1.x = acc[i][4] + b1.x; o1.y = acc[i][5] + b1.y;
                o1.z = acc[i][6] + b1.z; o1.w = acc[i][7] + b1.w;
                *(float4*)&Y[(size_t)gr * FOUT + HO + cg * 4] = o1;
            }
        }
    }
}

// ---------------------------------------------------------------------------
// Wave-per-segment gather-sum, float4 lanes. W=F/4 lanes cover one row with
// dwordx4 loads; H=64/W rows in flight per wave instruction (2/4/8 for
// F=128/64/32). Segment id wave-uniform -> scalar offs/lst; unroll x4 ->
// 4H rows in flight; shfl_xor tree combines the H sub-groups.
// ---------------------------------------------------------------------------
template<int F, bool RELU>
__global__ __launch_bounds__(256) void seg_gather_v4(
    const float* __restrict__ SRC, const int* __restrict__ offs,
    const int* __restrict__ lst, const float* __restrict__ inv,
    float* __restrict__ DST, int nseg)
{
    constexpr int W = F / 4;     // lanes per row
    constexpr int H = 64 / W;    // rows in flight
    int s = blockIdx.x * 4 + (threadIdx.x >> 6);
    s = __builtin_amdgcn_readfirstlane(s);
    if (s >= nseg) return;
    const int lane = threadIdx.x & 63;
    const int h = lane / W, c = lane % W;
    const int start = offs[s], end = offs[s + 1];
    const float* srcl = SRC + c * 4;
    float ax = 0.f, ay = 0.f, az = 0.f, aw = 0.f;
    int p = start + h;
    for (; p + 3 * H < end; p += 4 * H) {
        int r0 = lst[p], r1 = lst[p + H], r2 = lst[p + 2 * H], r3 = lst[p + 3 * H];
        float4 a0 = *(const float4*)(srcl + (size_t)r0 * F);
        float4 a1 = *(const float4*)(srcl + (size_t)r1 * F);
        float4 a2 = *(const float4*)(srcl + (size_t)r2 * F);
        float4 a3 = *(const float4*)(srcl + (size_t)r3 * F);
        ax += a0.x + a1.x + a2.x + a3.x;
        ay += a0.y + a1.y + a2.y + a3.y;
        az += a0.z + a1.z + a2.z + a3.z;
        aw += a0.w + a1.w + a2.w + a3.w;
    }
    for (; p < end; p += H) {
        int r = lst[p];
        float4 t = *(const float4*)(srcl + (size_t)r * F);
        ax += t.x; ay += t.y; az += t.z; aw += t.w;
    }
    #pragma unroll
    for (int d = W; d < 64; d <<= 1) {
        ax += __shfl_xor(ax, d);
        ay += __shfl_xor(ay, d);
        az += __shfl_xor(az, d);
        aw += __shfl_xor(aw, d);
    }
    if (lane < W) {
        float sc = inv[s];
        ax *= sc; ay *= sc; az *= sc; aw *= sc;
        if (RELU) {
            ax = fmaxf(ax, 0.f); ay = fmaxf(ay, 0.f);
            az = fmaxf(az, 0.f); aw = fmaxf(aw, 0.f);
        }
        float4 o; o.x = ax; o.y = ay; o.z = az; o.w = aw;
        *(float4*)(DST + (size_t)s * F + c * 4) = o;
    }
}

// ---------------------------------------------------------------------------
extern "C" void kernel_launch(void* const* d_in, const int* in_sizes, int n_in,
                              void* d_out, int out_size, void* d_ws, size_t ws_size,
                              hipStream_t stream)
{
    const float* x  = (const float*)d_in[0];
    const int* edge = (const int*)d_in[1];
    const float* w1 = (const float*)d_in[2];
    const float* b1 = (const float*)d_in[3];
    const float* w2 = (const float*)d_in[4];
    const float* b2 = (const float*)d_in[5];
    const float* w3 = (const float*)d_in[6];
    const float* b3 = (const float*)d_in[7];
    float* out = (float*)d_out;

    const int N = N_NODES, E = N_EDGES, NNZ = NNZ_TOT;
    const int* node_idx = edge;
    const int* edge_idx = edge + NNZ;

    uintptr_t base = (uintptr_t)d_ws;
    size_t off = 0;
    auto take = [&](size_t nbytes) -> void* {
        off = (off + 255) & ~(size_t)255;
        void* p = (void*)(base + off);
        off += nbytes;
        return p;
    };
    int*   offs_e  = (int*)  take((size_t)(E + 1) * 4);
    int*   offs_v  = (int*)  take((size_t)(N + 1) * 4);
    float* Binv    = (float*)take((size_t)E * 4);
    float* Dinv    = (float*)take((size_t)N * 4);
    int*   cntBE   = (int*)  take((size_t)NB_E * 4);
    int*   cntBV   = (int*)  take((size_t)NB_V * 4);
    int*   bktOffE = (int*)  take((size_t)(NB_E + 1) * 4);
    int*   bktOffV = (int*)  take((size_t)(NB_V + 1) * 4);
    int*   curBE   = (int*)  take((size_t)NB_E * 4);
    int*   curBV   = (int*)  take((size_t)NB_V * 4);
    int*   csrE    = (int*)  take((size_t)NNZ * 4);
    int*   csrV    = (int*)  take((size_t)NNZ * 4);
    float* xw      = (float*)take((size_t)N * 128 * 4);
    float* hA      = (float*)take((size_t)N * 128 * 4);
    float* hB      = (float*)take((size_t)N * 64 * 4);
    float* me      = (float*)take((size_t)E * 128 * 4);

    // bucket arrays alias hA: dead until the layer-1 node gather, long after
    // csr_finalize consumes them (single stream, sequential dependencies)
    unsigned int* bktE = (unsigned int*)hA;
    unsigned int* bktV = bktE + NNZ;

    hipMemsetAsync(cntBE, 0, (size_t)NB_E * 4, stream);
    hipMemsetAsync(cntBV, 0, (size_t)NB_V * 4, stream);

    bucket_count_kernel<<<(NNZ + 16383) / 16384, 1024, 0, stream>>>(
        node_idx, edge_idx, cntBE, cntBV, NNZ);
    bucket_scan_kernel<<<2, 1024, 0, stream>>>(
        cntBE, bktOffE, curBE, offs_e, cntBV, bktOffV, curBV, offs_v);
    bucket_write_kernel<<<(NNZ + 16383) / 16384, 1024, 0, stream>>>(
        node_idx, edge_idx, curBE, curBV, bktE, bktV, NNZ);
    csr_finalize_kernel<<<NB_E + NB_V, 256, 0, stream>>>(
        bktE, bktV, bktOffE, bktOffV, offs_e, offs_v, Binv, Dinv, csrE, csrV);

    // Layer 1: 128 -> 128   (BM=64: 782 blocks, thread tile 4x8)
    gemm_bias<128, 128, 64, 2><<<(N + 63) / 64, 256, 0, stream>>>(x, w1, b1, xw, N);
    seg_gather_v4<128, false><<<(E + 3) / 4, 256, 0, stream>>>(xw, offs_e, csrE, Binv, me, E);
    seg_gather_v4<128, true ><<<(N + 3) / 4, 256, 0, stream>>>(me, offs_v, csrV, Dinv, hA, N);

    // Layer 2: 128 -> 64    (BM=64: 782 blocks, thread tile 4x4)
    gemm_bias<128, 64, 64, 1><<<(N + 63) / 64, 256, 0, stream>>>(hA, w2, b2, xw, N);
    seg_gather_v4<64, false><<<(E + 3) / 4, 256, 0, stream>>>(xw, offs_e, csrE, Binv, me, E);
    seg_gather_v4<64, true ><<<(N + 3) / 4, 256, 0, stream>>>(me, offs_v, csrV, Dinv, hB, N);

    // Layer 3: 64 -> 32     (BM=128: 391 blocks, thread tile 4x4)
    gemm_bias<64, 32, 128, 1><<<(N + 127) / 128, 256, 0, stream>>>(hB, w3, b3, xw, N);
    seg_gather_v4<32, false><<<(E + 3) / 4, 256, 0, stream>>>(xw, offs_e, csrE, Binv, me, E);
    seg_gather_v4<32, true ><<<(N + 3) / 4, 256, 0, stream>>>(me, offs_v, csrV, Dinv, out, N);
}